// Round 1
// baseline (1386.691 us; speedup 1.0000x reference)
//
#include <hip/hip_runtime.h>
#include <hip/hip_bf16.h>
#include <math.h>

// SimpleFC: B=16, N=1024, E=64, H=4, dh=16. All f32.
#define NH 4
#define EE 64
#define BB 16
#define NN 1024
#define M_TOT (BB * NN)   // 16384 rows in the flattened [B*N, E] activation

// ---------- helpers ----------
__device__ __forceinline__ float4 ld4(const float* p) {
  return *reinterpret_cast<const float4*>(p);
}
__device__ __forceinline__ float dot4(float4 a, float4 b) {
  return a.x * b.x + a.y * b.y + a.z * b.z + a.w * b.w;
}
__device__ __forceinline__ void fma4(float4& o, float p, float4 v) {
  o.x = fmaf(p, v.x, o.x); o.y = fmaf(p, v.y, o.y);
  o.z = fmaf(p, v.z, o.z); o.w = fmaf(p, v.w, o.w);
}
__device__ __forceinline__ void scal4(float4& o, float c) {
  o.x *= c; o.y *= c; o.z *= c; o.w *= c;
}
__device__ __forceinline__ float wave_sum64(float v) {
  #pragma unroll
  for (int off = 32; off > 0; off >>= 1) v += __shfl_xor(v, off, 64);
  return v;
}

// ---------- timestep embedding: t_info = [sin(ang), cos(ang)], silu, 2 linear projections ----------
// grid 16 blocks (one per batch), 64 threads
__global__ __launch_bounds__(64) void temb_kernel(
    const float* __restrict__ t_int,
    const float* __restrict__ e1w, const float* __restrict__ e1b,
    const float* __restrict__ e2w, const float* __restrict__ e2b,
    float* __restrict__ temb1, float* __restrict__ temb2)
{
  int b = blockIdx.x, e = threadIdx.x;
  __shared__ float s_silu[EE];
  float t = t_int[b];
  int i = e & 31;
  // inv_freq = 10000^(-(2i)/64)
  float inv_freq = powf(10000.f, -(float)(2 * i) / (float)EE);
  float ang = t * inv_freq;
  float ti = (e < 32) ? sinf(ang) : cosf(ang);
  float sl = ti / (1.f + expf(-ti));   // silu
  s_silu[e] = sl;
  __syncthreads();
  float a1 = e1b[e], a2 = e2b[e];
  #pragma unroll 8
  for (int k = 0; k < EE; ++k) {
    float s = s_silu[k];
    a1 = fmaf(s, e1w[e * EE + k], a1);
    a2 = fmaf(s, e2w[e * EE + k], a2);
  }
  temb1[b * EE + e] = a1;
  temb2[b * EE + e] = a2;
}

// ---------- x = pos @ w_in^T + b_in + temb1[b] ----------
__global__ __launch_bounds__(256) void xinit_kernel(
    const float* __restrict__ pos, const float* __restrict__ w_in,
    const float* __restrict__ b_in, const float* __restrict__ temb1,
    float* __restrict__ x)
{
  int idx = blockIdx.x * 256 + threadIdx.x;   // [0, M_TOT*64)
  int e = idx & 63;
  int m = idx >> 6;
  int b = m >> 10;
  float p0 = pos[m * 3 + 0], p1 = pos[m * 3 + 1], p2 = pos[m * 3 + 2];
  float v = b_in[e] + temb1[b * EE + e];
  v = fmaf(p0, w_in[e * 3 + 0], v);
  v = fmaf(p1, w_in[e * 3 + 1], v);
  v = fmaf(p2, w_in[e * 3 + 2], v);
  x[idx] = v;
}

// ---------- LayerNorm over last dim (64). One wave per row, 4 rows/block ----------
__global__ __launch_bounds__(256) void ln_kernel(
    const float* __restrict__ in, float* __restrict__ out,
    const float* __restrict__ g, const float* __restrict__ beta)
{
  int row = blockIdx.x * 4 + (threadIdx.x >> 6);
  int e = threadIdx.x & 63;
  float x = in[row * EE + e];
  float mean = wave_sum64(x) * (1.f / EE);
  float d = x - mean;
  float var = wave_sum64(d * d) * (1.f / EE);
  float rs = rsqrtf(var + 1e-5f);
  out[row * EE + e] = d * rs * g[e] + beta[e];
}

// ---------- generic linear: out[m][j] = act_out( act_in(in)[m][:] . W[j][:] + bias[j] ) (+res)(+bvec) ----------
// 64-row tile in LDS (pad 65 -> conflict-free), wave-uniform weight addresses -> s_load,
// 4 output cols per thread amortize the LDS read.
template<int J, int AIN, int AOUT, bool ADDRES, bool ADDBV>
__global__ __launch_bounds__(256) void lin_kernel(
    const float* __restrict__ in, const float* __restrict__ W,
    const float* __restrict__ bias, const float* __restrict__ res,
    const float* __restrict__ bvec, float* __restrict__ out)
{
  __shared__ float s_in[64 * 65];
  const int tid = threadIdx.x;
  const int m0 = blockIdx.x * 64;
  // stage 64 rows x 64 cols (apply input activation)
  for (int t = tid; t < 64 * 16; t += 256) {
    int mrow = t >> 4, k4 = (t & 15) << 2;
    float4 v = ld4(in + (m0 + mrow) * 64 + k4);
    if (AIN == 1) {  // relu
      v.x = fmaxf(v.x, 0.f); v.y = fmaxf(v.y, 0.f);
      v.z = fmaxf(v.z, 0.f); v.w = fmaxf(v.w, 0.f);
    }
    float* d = &s_in[mrow * 65 + k4];
    d[0] = v.x; d[1] = v.y; d[2] = v.z; d[3] = v.w;
  }
  __syncthreads();
  const int r = tid & 63;
  const int wv = __builtin_amdgcn_readfirstlane(tid >> 6);   // wave id, provably uniform
  const int mrow = m0 + r;
  const int bidx = m0 >> 10;
  constexpr int JW = J / 4;   // j-range per wave (192->48, 64->16)
  for (int g0 = 0; g0 < JW; g0 += 4) {
    int jb = wv * JW + g0;                  // wave-uniform
    const float* w0 = W + jb * 64;
    float a0 = 0.f, a1 = 0.f, a2 = 0.f, a3 = 0.f;
    #pragma unroll 16
    for (int k = 0; k < 64; ++k) {
      float x = s_in[r * 65 + k];
      a0 = fmaf(x, w0[k],        a0);
      a1 = fmaf(x, w0[64 + k],   a1);
      a2 = fmaf(x, w0[128 + k],  a2);
      a3 = fmaf(x, w0[192 + k],  a3);
    }
    float vals[4] = {a0, a1, a2, a3};
    #pragma unroll
    for (int jj = 0; jj < 4; ++jj) {
      int j = jb + jj;
      float v = vals[jj] + bias[j];
      if (AOUT == 1) v = 0.5f * v * (1.f + erff(v * 0.70710678118f));  // exact gelu
      if (ADDBV)   v += bvec[bidx * J + j];
      if (ADDRES)  v += res[mrow * 64 + j];
      out[(size_t)mrow * J + j] = v;
    }
  }
}

// ---------- attention: one query row per lane; K/V rows broadcast from global (L1/L2) ----------
// grid = B*H*4 = 256 blocks, 256 threads. qkv layout [B*N][192]: q=0..63, k=64..127, v=128..191.
__global__ __launch_bounds__(256) void attn_kernel(
    const float* __restrict__ qkv, float* __restrict__ out)
{
  int blk = blockIdx.x;
  int bh = blk >> 2, qs = blk & 3;
  int b = bh >> 2, h = bh & 3;
  int q = qs * 256 + threadIdx.x;
  const float* qr = qkv + ((b << 10) + q) * 192 + h * 16;
  float4 q0 = ld4(qr), q1 = ld4(qr + 4), q2 = ld4(qr + 8), q3 = ld4(qr + 12);
  const float* kb = qkv + (size_t)(b << 10) * 192 + 64 + h * 16;
  float m = -3e30f, l = 0.f;
  float4 o0 = {0,0,0,0}, o1 = o0, o2 = o0, o3 = o0;
  #pragma unroll 2
  for (int j = 0; j < NN; ++j) {
    const float* kr = kb + j * 192;
    float4 k0 = ld4(kr), k1 = ld4(kr + 4), k2 = ld4(kr + 8), k3 = ld4(kr + 12);
    float s = (dot4(q0,k0) + dot4(q1,k1) + dot4(q2,k2) + dot4(q3,k3)) * 0.25f;
    if (s > m + 8.f) {            // rare rescale (T13); first iter: exp(-3e30-s)=0
      float c = __expf(m - s);
      m = s; l *= c;
      scal4(o0, c); scal4(o1, c); scal4(o2, c); scal4(o3, c);
    }
    float p = __expf(s - m);
    l += p;
    float4 v0 = ld4(kr + 64), v1 = ld4(kr + 68), v2 = ld4(kr + 72), v3 = ld4(kr + 76);
    fma4(o0, p, v0); fma4(o1, p, v1); fma4(o2, p, v2); fma4(o3, p, v3);
  }
  float inv = 1.f / l;
  scal4(o0, inv); scal4(o1, inv); scal4(o2, inv); scal4(o3, inv);
  float* orow = out + ((b << 10) + q) * 64 + h * 16;
  *reinterpret_cast<float4*>(orow + 0)  = o0;
  *reinterpret_cast<float4*>(orow + 4)  = o1;
  *reinterpret_cast<float4*>(orow + 8)  = o2;
  *reinterpret_cast<float4*>(orow + 12) = o3;
}

// ---------- final: out[m][c] = relu(x[m]) . w_out[c] + b_out[c], * mask[m] ----------
__global__ __launch_bounds__(256) void final_kernel(
    const float* __restrict__ x, const float* __restrict__ w_out,
    const float* __restrict__ b_out, const float* __restrict__ mask,
    float* __restrict__ out)
{
  int idx = blockIdx.x * 256 + threadIdx.x;  // [0, M_TOT*3)
  int mrow = idx / 3, c = idx - mrow * 3;
  float acc = b_out[c];
  #pragma unroll 8
  for (int k = 0; k < 64; ++k)
    acc = fmaf(fmaxf(x[mrow * 64 + k], 0.f), w_out[c * 64 + k], acc);
  out[idx] = acc * mask[mrow];
}

// ---------- host ----------
extern "C" void kernel_launch(void* const* d_in, const int* in_sizes, int n_in,
                              void* d_out, int out_size, void* d_ws, size_t ws_size,
                              hipStream_t stream)
{
  const float* pos    = (const float*)d_in[0];
  const float* t_int  = (const float*)d_in[1];
  const float* nmask  = (const float*)d_in[2];
  const float* w_in   = (const float*)d_in[3];
  const float* b_in   = (const float*)d_in[4];
  const float* w_mid  = (const float*)d_in[5];
  const float* b_mid  = (const float*)d_in[6];
  const float* w_out  = (const float*)d_in[7];
  const float* b_out  = (const float*)d_in[8];
  const float* e1w    = (const float*)d_in[9];
  const float* e1b    = (const float*)d_in[10];
  const float* e2w    = (const float*)d_in[11];
  const float* e2b    = (const float*)d_in[12];
  const float* const* SA1 = (const float* const*)(d_in + 13);
  const float* const* SA2 = (const float* const*)(d_in + 25);

  float* ws    = (float*)d_ws;
  float* temb1 = ws;                                 // 1024
  float* temb2 = ws + 1024;                          // 1024
  float* X     = ws + 2048;                          // 1M
  float* Hbuf  = X    + (size_t)M_TOT * 64;          // 1M
  float* QKV   = Hbuf + (size_t)M_TOT * 64;          // 3M
  float* Abuf  = QKV  + (size_t)M_TOT * 192;         // 1M
  float* X2    = Abuf + (size_t)M_TOT * 64;          // 1M

  temb_kernel<<<BB, 64, 0, stream>>>(t_int, e1w, e1b, e2w, e2b, temb1, temb2);
  xinit_kernel<<<(M_TOT * 64) / 256, 256, 0, stream>>>(pos, w_in, b_in, temb1, X);

  auto run_sa = [&](const float* const* P, float* Xp) {
    // P: ln_g, ln_b, qkv_w, qkv_b, out_w, out_b, fln_g, fln_b, f1_w, f1_b, f2_w, f2_b
    ln_kernel<<<M_TOT / 4, 256, 0, stream>>>(Xp, Hbuf, P[0], P[1]);
    lin_kernel<192, 0, 0, false, false><<<M_TOT / 64, 256, 0, stream>>>(
        Hbuf, P[2], P[3], nullptr, nullptr, QKV);
    attn_kernel<<<BB * NH * 4, 256, 0, stream>>>(QKV, Abuf);
    lin_kernel<64, 0, 0, true, false><<<M_TOT / 64, 256, 0, stream>>>(
        Abuf, P[4], P[5], Xp, nullptr, Xp);
    ln_kernel<<<M_TOT / 4, 256, 0, stream>>>(Xp, Hbuf, P[6], P[7]);
    lin_kernel<64, 0, 1, false, false><<<M_TOT / 64, 256, 0, stream>>>(
        Hbuf, P[8], P[9], nullptr, nullptr, Abuf);
    lin_kernel<64, 0, 0, true, false><<<M_TOT / 64, 256, 0, stream>>>(
        Abuf, P[10], P[11], Xp, nullptr, Xp);
  };

  run_sa(SA1, X);
  lin_kernel<64, 1, 0, false, true><<<M_TOT / 64, 256, 0, stream>>>(
      X, w_mid, b_mid, nullptr, temb2, X2);
  run_sa(SA2, X2);
  final_kernel<<<(M_TOT * 3) / 256, 256, 0, stream>>>(X2, w_out, b_out, nmask, (float*)d_out);
}

// Round 2
// 298.240 us; speedup vs baseline: 4.6496x; 4.6496x over previous
//
#include <hip/hip_runtime.h>
#include <hip/hip_bf16.h>
#include <math.h>

// SimpleFC: B=16, N=1024, E=64, H=4, dh=16.
#define NH 4
#define EE 64
#define BB 16
#define NN 1024
#define M_TOT (BB * NN)   // 16384 rows in the flattened [B*N, E] activation

typedef short bf16x4 __attribute__((ext_vector_type(4)));
typedef float f32x4 __attribute__((ext_vector_type(4)));

// ---------- helpers ----------
__device__ __forceinline__ float4 ld4(const float* p) {
  return *reinterpret_cast<const float4*>(p);
}
__device__ __forceinline__ float wave_sum64(float v) {
  #pragma unroll
  for (int off = 32; off > 0; off >>= 1) v += __shfl_xor(v, off, 64);
  return v;
}
// branchless f32 -> bf16 RNE (inputs are finite positive here)
__device__ __forceinline__ unsigned short f2bf(float f) {
  union { float f; unsigned int u; } x; x.f = f;
  unsigned int r = x.u + 0x7FFFu + ((x.u >> 16) & 1u);
  return (unsigned short)(r >> 16);
}

// ---------- timestep embedding ----------
__global__ __launch_bounds__(64) void temb_kernel(
    const float* __restrict__ t_int,
    const float* __restrict__ e1w, const float* __restrict__ e1b,
    const float* __restrict__ e2w, const float* __restrict__ e2b,
    float* __restrict__ temb1, float* __restrict__ temb2)
{
  int b = blockIdx.x, e = threadIdx.x;
  __shared__ float s_silu[EE];
  float t = t_int[b];
  int i = e & 31;
  float inv_freq = powf(10000.f, -(float)(2 * i) / (float)EE);
  float ang = t * inv_freq;
  float ti = (e < 32) ? sinf(ang) : cosf(ang);
  float sl = ti / (1.f + expf(-ti));   // silu
  s_silu[e] = sl;
  __syncthreads();
  float a1 = e1b[e], a2 = e2b[e];
  #pragma unroll 8
  for (int k = 0; k < EE; ++k) {
    float s = s_silu[k];
    a1 = fmaf(s, e1w[e * EE + k], a1);
    a2 = fmaf(s, e2w[e * EE + k], a2);
  }
  temb1[b * EE + e] = a1;
  temb2[b * EE + e] = a2;
}

// ---------- x = pos @ w_in^T + b_in + temb1[b] ----------
__global__ __launch_bounds__(256) void xinit_kernel(
    const float* __restrict__ pos, const float* __restrict__ w_in,
    const float* __restrict__ b_in, const float* __restrict__ temb1,
    float* __restrict__ x)
{
  int idx = blockIdx.x * 256 + threadIdx.x;
  int e = idx & 63;
  int m = idx >> 6;
  int b = m >> 10;
  float p0 = pos[m * 3 + 0], p1 = pos[m * 3 + 1], p2 = pos[m * 3 + 2];
  float v = b_in[e] + temb1[b * EE + e];
  v = fmaf(p0, w_in[e * 3 + 0], v);
  v = fmaf(p1, w_in[e * 3 + 1], v);
  v = fmaf(p2, w_in[e * 3 + 2], v);
  x[idx] = v;
}

// ---------- LayerNorm over last dim (64) ----------
__global__ __launch_bounds__(256) void ln_kernel(
    const float* __restrict__ in, float* __restrict__ out,
    const float* __restrict__ g, const float* __restrict__ beta)
{
  int row = blockIdx.x * 4 + (threadIdx.x >> 6);
  int e = threadIdx.x & 63;
  float x = in[row * EE + e];
  float mean = wave_sum64(x) * (1.f / EE);
  float d = x - mean;
  float var = wave_sum64(d * d) * (1.f / EE);
  float rs = rsqrtf(var + 1e-5f);
  out[row * EE + e] = d * rs * g[e] + beta[e];
}

// ---------- generic linear ----------
// OBF16: store output as bf16 (used for QKV so attention reads bf16 directly)
template<int J, int AIN, int AOUT, bool ADDRES, bool ADDBV, bool OBF16>
__global__ __launch_bounds__(256) void lin_kernel(
    const float* __restrict__ in, const float* __restrict__ W,
    const float* __restrict__ bias, const float* __restrict__ res,
    const float* __restrict__ bvec, float* __restrict__ out)
{
  __shared__ float s_in[64 * 65];
  const int tid = threadIdx.x;
  const int m0 = blockIdx.x * 64;
  for (int t = tid; t < 64 * 16; t += 256) {
    int mrow = t >> 4, k4 = (t & 15) << 2;
    float4 v = ld4(in + (m0 + mrow) * 64 + k4);
    if (AIN == 1) {
      v.x = fmaxf(v.x, 0.f); v.y = fmaxf(v.y, 0.f);
      v.z = fmaxf(v.z, 0.f); v.w = fmaxf(v.w, 0.f);
    }
    float* d = &s_in[mrow * 65 + k4];
    d[0] = v.x; d[1] = v.y; d[2] = v.z; d[3] = v.w;
  }
  __syncthreads();
  const int r = tid & 63;
  const int wv = __builtin_amdgcn_readfirstlane(tid >> 6);
  const int mrow = m0 + r;
  const int bidx = m0 >> 10;
  constexpr int JW = J / 4;
  for (int g0 = 0; g0 < JW; g0 += 4) {
    int jb = wv * JW + g0;
    const float* w0 = W + jb * 64;
    float a0 = 0.f, a1 = 0.f, a2 = 0.f, a3 = 0.f;
    #pragma unroll 16
    for (int k = 0; k < 64; ++k) {
      float x = s_in[r * 65 + k];
      a0 = fmaf(x, w0[k],        a0);
      a1 = fmaf(x, w0[64 + k],   a1);
      a2 = fmaf(x, w0[128 + k],  a2);
      a3 = fmaf(x, w0[192 + k],  a3);
    }
    float vals[4] = {a0, a1, a2, a3};
    #pragma unroll
    for (int jj = 0; jj < 4; ++jj) {
      int j = jb + jj;
      float v = vals[jj] + bias[j];
      if (AOUT == 1) v = 0.5f * v * (1.f + erff(v * 0.70710678118f));
      if (ADDBV)   v += bvec[bidx * J + j];
      if (ADDRES)  v += res[mrow * 64 + j];
      if (OBF16) ((unsigned short*)out)[(size_t)mrow * J + j] = f2bf(v);
      else       out[(size_t)mrow * J + j] = v;
    }
  }
}

// ---------- MFMA flash attention ----------
// qkv: bf16 [B*N][192] (q 0..63 | k 64..127 | v 128..191). out: f32 [B*N][64].
// One wave = 16 queries of one (b,h). Transposed formulation:
//   S^T = mfma(A=K_chunk[kv16 x dh16], B=Q^T)   lane: S^T[kv=4*lg+r][q=lr]
//   O^T += mfma(A=V^T_chunk, B=P^T)             P^T frag == S^T C-layout (no xlane)
// Universal frag pattern: row = lane&15, k-chunk = (lane>>4)*4.
__global__ __launch_bounds__(256) void attn_mfma_kernel(
    const unsigned short* __restrict__ qkv, float* __restrict__ out)
{
  const int tid = threadIdx.x;
  const int w = tid >> 6, l = tid & 63;
  const int lr = l & 15, lg = l >> 4;
  const int blk = blockIdx.x;          // bh*16 + qblk
  const int bh = blk >> 4, qblk = blk & 15;
  const int b = bh >> 2, h = bh & 3;
  const int q0 = qblk * 64 + w * 16;

  const unsigned short* base = qkv + (size_t)(b << 10) * 192;
  // Q B-frag: Q[q0+lr][h*16 + 4*lg .. +3]
  bf16x4 qf = __builtin_bit_cast(bf16x4,
      *(const uint2*)(base + (q0 + lr) * 192 + h * 16 + 4 * lg));
  // K A-frag pointer: K[16c+lr][4*lg..+3]
  const unsigned short* kptr = base + lr * 192 + 64 + h * 16 + 4 * lg;
  // V^T pointer: V[16c + 4*lg + i][lr] (4 scalar bf16 loads, imm offsets)
  const unsigned short* vptr = base + (4 * lg) * 192 + 128 + h * 16 + lr;

  float m = -3e30f, lsum = 0.f;
  f32x4 o = {0.f, 0.f, 0.f, 0.f};

  #pragma unroll 2
  for (int c = 0; c < 64; ++c) {
    bf16x4 kf = __builtin_bit_cast(bf16x4, *(const uint2*)kptr);
    f32x4 zero = {0.f, 0.f, 0.f, 0.f};
    f32x4 st = __builtin_amdgcn_mfma_f32_16x16x16bf16_1k(kf, qf, zero, 0, 0, 0);
    unsigned short v0 = vptr[0], v1 = vptr[192], v2 = vptr[384], v3 = vptr[576];

    float s0 = st[0] * 0.25f, s1 = st[1] * 0.25f;
    float s2 = st[2] * 0.25f, s3 = st[3] * 0.25f;
    float cmax = fmaxf(fmaxf(s0, s1), fmaxf(s2, s3));
    cmax = fmaxf(cmax, __shfl_xor(cmax, 16));
    cmax = fmaxf(cmax, __shfl_xor(cmax, 32));
    float mnew = fmaxf(m, cmax);
    float fac = __expf(m - mnew);       // first chunk: exp(-inf) = 0
    m = mnew;
    float p0 = __expf(s0 - m), p1 = __expf(s1 - m);
    float p2 = __expf(s2 - m), p3 = __expf(s3 - m);
    float cs = (p0 + p1) + (p2 + p3);
    cs += __shfl_xor(cs, 16);
    cs += __shfl_xor(cs, 32);
    lsum = lsum * fac + cs;
    o[0] *= fac; o[1] *= fac; o[2] *= fac; o[3] *= fac;

    unsigned int pu0 = (unsigned int)f2bf(p0) | ((unsigned int)f2bf(p1) << 16);
    unsigned int pu1 = (unsigned int)f2bf(p2) | ((unsigned int)f2bf(p3) << 16);
    uint2 puu; puu.x = pu0; puu.y = pu1;
    bf16x4 pf = __builtin_bit_cast(bf16x4, puu);
    unsigned int vu0 = (unsigned int)v0 | ((unsigned int)v1 << 16);
    unsigned int vu1 = (unsigned int)v2 | ((unsigned int)v3 << 16);
    uint2 vuu; vuu.x = vu0; vuu.y = vu1;
    bf16x4 vf = __builtin_bit_cast(bf16x4, vuu);

    o = __builtin_amdgcn_mfma_f32_16x16x16bf16_1k(vf, pf, o, 0, 0, 0);

    kptr += 16 * 192; vptr += 16 * 192;
  }
  float inv = 1.f / lsum;
  float4 res;
  res.x = o[0] * inv; res.y = o[1] * inv; res.z = o[2] * inv; res.w = o[3] * inv;
  *reinterpret_cast<float4*>(out + ((size_t)(b << 10) + q0 + lr) * 64 + h * 16 + 4 * lg) = res;
}

// ---------- final ----------
__global__ __launch_bounds__(256) void final_kernel(
    const float* __restrict__ x, const float* __restrict__ w_out,
    const float* __restrict__ b_out, const float* __restrict__ mask,
    float* __restrict__ out)
{
  int idx = blockIdx.x * 256 + threadIdx.x;
  int mrow = idx / 3, c = idx - mrow * 3;
  float acc = b_out[c];
  #pragma unroll 8
  for (int k = 0; k < 64; ++k)
    acc = fmaf(fmaxf(x[mrow * 64 + k], 0.f), w_out[c * 64 + k], acc);
  out[idx] = acc * mask[mrow];
}

// ---------- host ----------
extern "C" void kernel_launch(void* const* d_in, const int* in_sizes, int n_in,
                              void* d_out, int out_size, void* d_ws, size_t ws_size,
                              hipStream_t stream)
{
  const float* pos    = (const float*)d_in[0];
  const float* t_int  = (const float*)d_in[1];
  const float* nmask  = (const float*)d_in[2];
  const float* w_in   = (const float*)d_in[3];
  const float* b_in   = (const float*)d_in[4];
  const float* w_mid  = (const float*)d_in[5];
  const float* b_mid  = (const float*)d_in[6];
  const float* w_out  = (const float*)d_in[7];
  const float* b_out  = (const float*)d_in[8];
  const float* e1w    = (const float*)d_in[9];
  const float* e1b    = (const float*)d_in[10];
  const float* e2w    = (const float*)d_in[11];
  const float* e2b    = (const float*)d_in[12];
  const float* const* SA1 = (const float* const*)(d_in + 13);
  const float* const* SA2 = (const float* const*)(d_in + 25);

  float* ws    = (float*)d_ws;
  float* temb1 = ws;                                 // 1024
  float* temb2 = ws + 1024;                          // 1024
  float* X     = ws + 2048;
  float* Hbuf  = X    + (size_t)M_TOT * 64;
  float* QKV   = Hbuf + (size_t)M_TOT * 64;          // bf16 [M_TOT][192] (aliased)
  float* Abuf  = QKV  + (size_t)M_TOT * 192;         // f32 region reserved
  float* X2    = Abuf + (size_t)M_TOT * 64;

  temb_kernel<<<BB, 64, 0, stream>>>(t_int, e1w, e1b, e2w, e2b, temb1, temb2);
  xinit_kernel<<<(M_TOT * 64) / 256, 256, 0, stream>>>(pos, w_in, b_in, temb1, X);

  auto run_sa = [&](const float* const* P, float* Xp) {
    ln_kernel<<<M_TOT / 4, 256, 0, stream>>>(Xp, Hbuf, P[0], P[1]);
    lin_kernel<192, 0, 0, false, false, true><<<M_TOT / 64, 256, 0, stream>>>(
        Hbuf, P[2], P[3], nullptr, nullptr, QKV);
    attn_mfma_kernel<<<64 * 16, 256, 0, stream>>>((const unsigned short*)QKV, Abuf);
    lin_kernel<64, 0, 0, true, false, false><<<M_TOT / 64, 256, 0, stream>>>(
        Abuf, P[4], P[5], Xp, nullptr, Xp);
    ln_kernel<<<M_TOT / 4, 256, 0, stream>>>(Xp, Hbuf, P[6], P[7]);
    lin_kernel<64, 0, 1, false, false, false><<<M_TOT / 64, 256, 0, stream>>>(
        Hbuf, P[8], P[9], nullptr, nullptr, Abuf);
    lin_kernel<64, 0, 0, true, false, false><<<M_TOT / 64, 256, 0, stream>>>(
        Abuf, P[10], P[11], Xp, nullptr, Xp);
  };

  run_sa(SA1, X);
  lin_kernel<64, 1, 0, false, true, false><<<M_TOT / 64, 256, 0, stream>>>(
      X, w_mid, b_mid, nullptr, temb2, X2);
  run_sa(SA2, X2);
  final_kernel<<<(M_TOT * 3) / 256, 256, 0, stream>>>(X2, w_out, b_out, nmask, (float*)d_out);
}

// Round 3
// 140.681 us; speedup vs baseline: 9.8570x; 2.1200x over previous
//
#include <hip/hip_runtime.h>
#include <hip/hip_bf16.h>
#include <math.h>

// SimpleFC: B=16, N=1024, E=64, H=4, dh=16.
#define NH 4
#define EE 64
#define BB 16
#define NN 1024
#define M_TOT (BB * NN)
#define QSCALE 0.3606737602222409f   // 0.25 * log2(e)

typedef short bf16x4 __attribute__((ext_vector_type(4)));
typedef float f32x4 __attribute__((ext_vector_type(4)));
typedef unsigned short ushort_t;

// ---------- helpers ----------
__device__ __forceinline__ ushort_t f2bf(float f) {   // RNE f32->bf16
  union { float f; unsigned int u; } x; x.f = f;
  unsigned int r = x.u + 0x7FFFu + ((x.u >> 16) & 1u);
  return (ushort_t)(r >> 16);
}
__device__ __forceinline__ bf16x4 pack4(float a, float b, float c, float d) {
  uint2 u;
  u.x = (unsigned int)f2bf(a) | ((unsigned int)f2bf(b) << 16);
  u.y = (unsigned int)f2bf(c) | ((unsigned int)f2bf(d) << 16);
  return __builtin_bit_cast(bf16x4, u);
}
__device__ __forceinline__ bf16x4 ldbf4(const ushort_t* p) {
  return __builtin_bit_cast(bf16x4, *reinterpret_cast<const uint2*>(p));
}

// ---------- weight conversion: f32 -> bf16, once per launch ----------
__global__ __launch_bounds__(256) void cvtw_kernel(
    const float* a0, const float* a1, const float* a2, const float* a3,
    const float* a4, const float* a5, const float* a6, const float* a7,
    const float* a8, ushort_t* __restrict__ dst)
{
  const int off[9] = {0, 12288, 16384, 20480, 24576, 36864, 40960, 45056, 49152};
  const int sz[9]  = {12288, 4096, 4096, 4096, 12288, 4096, 4096, 4096, 4096};
  const float* srcs[9] = {a0, a1, a2, a3, a4, a5, a6, a7, a8};
  int s = blockIdx.y;
  const float* src = srcs[s];
  for (int i = blockIdx.x * 256 + threadIdx.x; i < sz[s]; i += gridDim.x * 256)
    dst[off[s] + i] = f2bf(src[i]);
}

// ---------- timestep embedding ----------
__global__ __launch_bounds__(64) void temb_kernel(
    const float* __restrict__ t_int,
    const float* __restrict__ e1w, const float* __restrict__ e1b,
    const float* __restrict__ e2w, const float* __restrict__ e2b,
    float* __restrict__ temb1, float* __restrict__ temb2)
{
  int b = blockIdx.x, e = threadIdx.x;
  __shared__ float s_silu[EE];
  float t = t_int[b];
  int i = e & 31;
  float inv_freq = powf(10000.f, -(float)(2 * i) / (float)EE);
  float ang = t * inv_freq;
  float ti = (e < 32) ? sinf(ang) : cosf(ang);
  s_silu[e] = ti / (1.f + expf(-ti));
  __syncthreads();
  float a1 = e1b[e], a2 = e2b[e];
  #pragma unroll 8
  for (int k = 0; k < EE; ++k) {
    float s = s_silu[k];
    a1 = fmaf(s, e1w[e * EE + k], a1);
    a2 = fmaf(s, e2w[e * EE + k], a2);
  }
  temb1[b * EE + e] = a1;
  temb2[b * EE + e] = a2;
}

// ---------- [xinit +] LN + QKV projection ----------
// Writes Qb [b][h][q][16] (pre-scaled by QSCALE), Kb [b][h][kv][16], VT [b][h][d][kv], all bf16.
template<bool XINIT>
__global__ __launch_bounds__(256) void qkv_kernel(
    const float* __restrict__ Xin, const float* __restrict__ pos,
    const float* __restrict__ w_in, const float* __restrict__ b_in,
    const float* __restrict__ temb1, float* __restrict__ Xout,
    const float* __restrict__ g, const float* __restrict__ beta,
    const ushort_t* __restrict__ Wq, const float* __restrict__ bq,
    ushort_t* __restrict__ Qb, ushort_t* __restrict__ Kb, ushort_t* __restrict__ VT)
{
  __shared__ ushort_t s_h[64 * 68];
  const int tid = threadIdx.x;
  const int m0 = blockIdx.x * 64;
  const int b = m0 >> 10;
  const int r = tid >> 2, c0 = (tid & 3) * 16;
  float v[16];
  if (XINIT) {
    const float* pr = pos + (size_t)(m0 + r) * 3;
    float p0 = pr[0], p1 = pr[1], p2 = pr[2];
    #pragma unroll
    for (int j = 0; j < 16; ++j) {
      int c = c0 + j;
      float t = b_in[c] + temb1[b * EE + c];
      t = fmaf(p0, w_in[c * 3 + 0], t);
      t = fmaf(p1, w_in[c * 3 + 1], t);
      t = fmaf(p2, w_in[c * 3 + 2], t);
      v[j] = t;
    }
    float4* xo = (float4*)(Xout + (size_t)(m0 + r) * 64 + c0);
    #pragma unroll
    for (int j = 0; j < 4; ++j) {
      float4 t4; t4.x = v[4*j]; t4.y = v[4*j+1]; t4.z = v[4*j+2]; t4.w = v[4*j+3];
      xo[j] = t4;
    }
  } else {
    const float4* xi = (const float4*)(Xin + (size_t)(m0 + r) * 64 + c0);
    #pragma unroll
    for (int j = 0; j < 4; ++j) {
      float4 t4 = xi[j];
      v[4*j] = t4.x; v[4*j+1] = t4.y; v[4*j+2] = t4.z; v[4*j+3] = t4.w;
    }
  }
  // LN (4 threads per row, shfl within quad)
  float s = 0.f;
  #pragma unroll
  for (int j = 0; j < 16; ++j) s += v[j];
  s += __shfl_xor(s, 1); s += __shfl_xor(s, 2);
  float mean = s * (1.f / EE);
  float qv = 0.f;
  #pragma unroll
  for (int j = 0; j < 16; ++j) { float d = v[j] - mean; qv += d * d; }
  qv += __shfl_xor(qv, 1); qv += __shfl_xor(qv, 2);
  float rs = rsqrtf(qv * (1.f / EE) + 1e-5f);
  unsigned int* sh = (unsigned int*)&s_h[r * 68 + c0];
  #pragma unroll
  for (int j = 0; j < 16; j += 2) {
    float h0 = (v[j]     - mean) * rs * g[c0 + j]     + beta[c0 + j];
    float h1 = (v[j + 1] - mean) * rs * g[c0 + j + 1] + beta[c0 + j + 1];
    sh[j >> 1] = (unsigned int)f2bf(h0) | ((unsigned int)f2bf(h1) << 16);
  }
  __syncthreads();
  // GEMM: 192 cols
  const int w = tid >> 6, l = tid & 63, lr = l & 15, lg = l >> 4;
  const int wm0 = w * 16;
  bf16x4 af[4];
  #pragma unroll
  for (int kb = 0; kb < 4; ++kb)
    af[kb] = ldbf4(&s_h[(wm0 + lr) * 68 + kb * 16 + 4 * lg]);
  const int qloc = (m0 & 1023) + wm0 + 4 * lg;   // + rr
  #pragma unroll
  for (int jt = 0; jt < 12; ++jt) {
    f32x4 acc = {0.f, 0.f, 0.f, 0.f};
    const ushort_t* wb = Wq + (jt * 16 + lr) * 64 + 4 * lg;
    #pragma unroll
    for (int kb = 0; kb < 4; ++kb)
      acc = __builtin_amdgcn_mfma_f32_16x16x16bf16_1k(af[kb], ldbf4(wb + kb * 16), acc, 0, 0, 0);
    float bias = bq[jt * 16 + lr];
    if (jt < 4) {
      ushort_t* dst = Qb + ((size_t)(b * NH + jt) * NN + qloc) * 16 + lr;
      #pragma unroll
      for (int rr = 0; rr < 4; ++rr) dst[rr * 16] = f2bf((acc[rr] + bias) * QSCALE);
    } else if (jt < 8) {
      ushort_t* dst = Kb + ((size_t)(b * NH + jt - 4) * NN + qloc) * 16 + lr;
      #pragma unroll
      for (int rr = 0; rr < 4; ++rr) dst[rr * 16] = f2bf(acc[rr] + bias);
    } else {
      ushort_t* dst = VT + ((size_t)(b * NH + jt - 8) * 16 + lr) * NN + qloc;
      bf16x4 pv = pack4(acc[0] + bias, acc[1] + bias, acc[2] + bias, acc[3] + bias);
      *reinterpret_cast<uint2*>(dst) = __builtin_bit_cast(uint2, pv);
    }
  }
}

// ---------- MFMA flash attention, no-max softmax (scores bounded), deferred l-reduce ----------
__global__ __launch_bounds__(256) void attn_kernel(
    const ushort_t* __restrict__ Qb, const ushort_t* __restrict__ Kb,
    const ushort_t* __restrict__ VT, ushort_t* __restrict__ Ab)
{
  const int tid = threadIdx.x, w = tid >> 6, l = tid & 63, lr = l & 15, lg = l >> 4;
  const int blk = blockIdx.x, bh = blk >> 4, qblk = blk & 15;
  const int q0 = qblk * 64 + w * 16;
  bf16x4 qf = ldbf4(Qb + ((size_t)bh * NN + q0 + lr) * 16 + 4 * lg);
  const ushort_t* kp = Kb + (size_t)bh * NN * 16 + lr * 16 + 4 * lg;
  const ushort_t* vp = VT + ((size_t)bh * 16 + lr) * NN + 4 * lg;
  f32x4 o = {0.f, 0.f, 0.f, 0.f};
  float psum = 0.f;
  #pragma unroll 4
  for (int c = 0; c < 64; ++c) {
    bf16x4 kf = ldbf4(kp + c * 256);
    bf16x4 vf = ldbf4(vp + c * 16);
    f32x4 z = {0.f, 0.f, 0.f, 0.f};
    f32x4 st = __builtin_amdgcn_mfma_f32_16x16x16bf16_1k(kf, qf, z, 0, 0, 0);
    float p0 = __builtin_amdgcn_exp2f(st[0]);
    float p1 = __builtin_amdgcn_exp2f(st[1]);
    float p2 = __builtin_amdgcn_exp2f(st[2]);
    float p3 = __builtin_amdgcn_exp2f(st[3]);
    psum += (p0 + p1) + (p2 + p3);
    bf16x4 pf = pack4(p0, p1, p2, p3);
    o = __builtin_amdgcn_mfma_f32_16x16x16bf16_1k(vf, pf, o, 0, 0, 0);
  }
  psum += __shfl_xor(psum, 16);
  psum += __shfl_xor(psum, 32);
  float inv = 1.f / psum;
  const int b = bh >> 2, h = bh & 3;
  ushort_t* dst = Ab + ((size_t)b * NN + q0 + lr) * 64 + h * 16 + 4 * lg;
  bf16x4 ov = pack4(o[0] * inv, o[1] * inv, o[2] * inv, o[3] * inv);
  *reinterpret_cast<uint2*>(dst) = __builtin_bit_cast(uint2, ov);
}

// ---------- fused: out-proj + res -> LN -> F1(gelu) -> F2 + res -> {mid | final} ----------
template<int TAIL>   // 0 = mid-linear tail (writes X2 f32), 1 = final 3-col tail (writes d_out)
__global__ __launch_bounds__(256) void ffn_kernel(
    const ushort_t* __restrict__ Ab, const float* __restrict__ Xres,
    const ushort_t* __restrict__ Wo, const float* __restrict__ bo,
    const float* __restrict__ g, const float* __restrict__ beta,
    const ushort_t* __restrict__ W1, const float* __restrict__ b1,
    const ushort_t* __restrict__ W2, const float* __restrict__ b2,
    const ushort_t* __restrict__ Wt, const float* __restrict__ bt,
    const float* __restrict__ temb2,
    const float* __restrict__ wout3, const float* __restrict__ bout3,
    const float* __restrict__ mask,
    float* __restrict__ Out)
{
  __shared__ ushort_t s_b1[64 * 68];
  __shared__ ushort_t s_b2[64 * 68];
  __shared__ float s_av[64 * 66];
  __shared__ float s_rs[64 * 66];
  const int tid = threadIdx.x;
  const int m0 = blockIdx.x * 64, b = m0 >> 10;
  const int r = tid >> 2, c0 = (tid & 3) * 16;
  // stage attn-out (bf16) + residual X (f32)
  {
    const uint2* ai = (const uint2*)(Ab + (size_t)(m0 + r) * 64 + c0);
    uint2* ao = (uint2*)&s_b1[r * 68 + c0];
    #pragma unroll
    for (int j = 0; j < 4; ++j) ao[j] = ai[j];
    const float2* xi = (const float2*)(Xres + (size_t)(m0 + r) * 64 + c0);
    float2* xo = (float2*)&s_rs[r * 66 + c0];
    #pragma unroll
    for (int j = 0; j < 8; ++j) xo[j] = xi[j];
  }
  __syncthreads();
  const int w = tid >> 6, l = tid & 63, lr = l & 15, lg = l >> 4;
  const int wm0 = w * 16;
  // G1: av = A @ Wo^T + bo + Xres
  {
    bf16x4 af[4];
    #pragma unroll
    for (int kb = 0; kb < 4; ++kb)
      af[kb] = ldbf4(&s_b1[(wm0 + lr) * 68 + kb * 16 + 4 * lg]);
    #pragma unroll
    for (int jt = 0; jt < 4; ++jt) {
      f32x4 acc = {0.f, 0.f, 0.f, 0.f};
      const ushort_t* wb = Wo + (jt * 16 + lr) * 64 + 4 * lg;
      #pragma unroll
      for (int kb = 0; kb < 4; ++kb)
        acc = __builtin_amdgcn_mfma_f32_16x16x16bf16_1k(af[kb], ldbf4(wb + kb * 16), acc, 0, 0, 0);
      float bias = bo[jt * 16 + lr];
      #pragma unroll
      for (int rr = 0; rr < 4; ++rr) {
        int m = wm0 + 4 * lg + rr;
        s_av[m * 66 + jt * 16 + lr] = acc[rr] + bias + s_rs[m * 66 + jt * 16 + lr];
      }
    }
  }
  __syncthreads();
  // LN(av) -> s_b1 (bf16)
  {
    float v[16];
    #pragma unroll
    for (int j = 0; j < 16; ++j) v[j] = s_av[r * 66 + c0 + j];
    float s = 0.f;
    #pragma unroll
    for (int j = 0; j < 16; ++j) s += v[j];
    s += __shfl_xor(s, 1); s += __shfl_xor(s, 2);
    float mean = s * (1.f / EE);
    float qv = 0.f;
    #pragma unroll
    for (int j = 0; j < 16; ++j) { float d = v[j] - mean; qv += d * d; }
    qv += __shfl_xor(qv, 1); qv += __shfl_xor(qv, 2);
    float rsd = rsqrtf(qv * (1.f / EE) + 1e-5f);
    unsigned int* sh = (unsigned int*)&s_b1[r * 68 + c0];
    #pragma unroll
    for (int j = 0; j < 16; j += 2) {
      float h0 = (v[j]     - mean) * rsd * g[c0 + j]     + beta[c0 + j];
      float h1 = (v[j + 1] - mean) * rsd * g[c0 + j + 1] + beta[c0 + j + 1];
      sh[j >> 1] = (unsigned int)f2bf(h0) | ((unsigned int)f2bf(h1) << 16);
    }
  }
  __syncthreads();
  // G2: h1 = gelu(h @ W1^T + b1) -> s_b2 (bf16)
  {
    bf16x4 af[4];
    #pragma unroll
    for (int kb = 0; kb < 4; ++kb)
      af[kb] = ldbf4(&s_b1[(wm0 + lr) * 68 + kb * 16 + 4 * lg]);
    #pragma unroll
    for (int jt = 0; jt < 4; ++jt) {
      f32x4 acc = {0.f, 0.f, 0.f, 0.f};
      const ushort_t* wb = W1 + (jt * 16 + lr) * 64 + 4 * lg;
      #pragma unroll
      for (int kb = 0; kb < 4; ++kb)
        acc = __builtin_amdgcn_mfma_f32_16x16x16bf16_1k(af[kb], ldbf4(wb + kb * 16), acc, 0, 0, 0);
      float bias = b1[jt * 16 + lr];
      #pragma unroll
      for (int rr = 0; rr < 4; ++rr) {
        float t = acc[rr] + bias;
        t = 0.5f * t * (1.f + erff(t * 0.70710678118f));
        s_b2[(wm0 + 4 * lg + rr) * 68 + jt * 16 + lr] = f2bf(t);
      }
    }
  }
  __syncthreads();
  // G3: sa = h1 @ W2^T + b2 + av
  {
    bf16x4 af[4];
    #pragma unroll
    for (int kb = 0; kb < 4; ++kb)
      af[kb] = ldbf4(&s_b2[(wm0 + lr) * 68 + kb * 16 + 4 * lg]);
    #pragma unroll
    for (int jt = 0; jt < 4; ++jt) {
      f32x4 acc = {0.f, 0.f, 0.f, 0.f};
      const ushort_t* wb = W2 + (jt * 16 + lr) * 64 + 4 * lg;
      #pragma unroll
      for (int kb = 0; kb < 4; ++kb)
        acc = __builtin_amdgcn_mfma_f32_16x16x16bf16_1k(af[kb], ldbf4(wb + kb * 16), acc, 0, 0, 0);
      float bias = b2[jt * 16 + lr];
      #pragma unroll
      for (int rr = 0; rr < 4; ++rr) {
        int m = wm0 + 4 * lg + rr;
        float sa = acc[rr] + bias + s_av[m * 66 + jt * 16 + lr];
        if (TAIL == 0) s_b1[m * 68 + jt * 16 + lr] = f2bf(fmaxf(sa, 0.f));
        else           s_rs[m * 66 + jt * 16 + lr] = sa;
      }
    }
  }
  __syncthreads();
  if (TAIL == 0) {
    // G4: X2 = relu(sa) @ Wmid^T + bmid + temb2[b]
    bf16x4 af[4];
    #pragma unroll
    for (int kb = 0; kb < 4; ++kb)
      af[kb] = ldbf4(&s_b1[(wm0 + lr) * 68 + kb * 16 + 4 * lg]);
    #pragma unroll
    for (int jt = 0; jt < 4; ++jt) {
      f32x4 acc = {0.f, 0.f, 0.f, 0.f};
      const ushort_t* wb = Wt + (jt * 16 + lr) * 64 + 4 * lg;
      #pragma unroll
      for (int kb = 0; kb < 4; ++kb)
        acc = __builtin_amdgcn_mfma_f32_16x16x16bf16_1k(af[kb], ldbf4(wb + kb * 16), acc, 0, 0, 0);
      float bias = bt[jt * 16 + lr] + temb2[b * EE + jt * 16 + lr];
      #pragma unroll
      for (int rr = 0; rr < 4; ++rr)
        Out[(size_t)(m0 + wm0 + 4 * lg + rr) * 64 + jt * 16 + lr] = acc[rr] + bias;
    }
  } else {
    if (tid < 192) {
      int row = tid / 3, c = tid - row * 3;
      float acc = bout3[c];
      #pragma unroll 8
      for (int k = 0; k < 64; ++k)
        acc = fmaf(fmaxf(s_rs[row * 66 + k], 0.f), wout3[c * 64 + k], acc);
      Out[(size_t)(m0 + row) * 3 + c] = acc * mask[m0 + row];
    }
  }
}

// ---------- host ----------
extern "C" void kernel_launch(void* const* d_in, const int* in_sizes, int n_in,
                              void* d_out, int out_size, void* d_ws, size_t ws_size,
                              hipStream_t stream)
{
  const float* pos    = (const float*)d_in[0];
  const float* t_int  = (const float*)d_in[1];
  const float* nmask  = (const float*)d_in[2];
  const float* w_in   = (const float*)d_in[3];
  const float* b_in   = (const float*)d_in[4];
  const float* w_mid  = (const float*)d_in[5];
  const float* b_mid  = (const float*)d_in[6];
  const float* w_out  = (const float*)d_in[7];
  const float* b_out  = (const float*)d_in[8];
  const float* e1w    = (const float*)d_in[9];
  const float* e1b    = (const float*)d_in[10];
  const float* e2w    = (const float*)d_in[11];
  const float* e2b    = (const float*)d_in[12];
  const float* const* SA1 = (const float* const*)(d_in + 13);
  const float* const* SA2 = (const float* const*)(d_in + 25);

  float* ws    = (float*)d_ws;
  float* temb1 = ws;
  float* temb2 = ws + 1024;
  float* X     = ws + 2048;
  float* X2    = X + (size_t)M_TOT * 64;
  ushort_t* ub = (ushort_t*)(X2 + (size_t)M_TOT * 64);
  ushort_t* Qb = ub;
  ushort_t* Kb = Qb + (size_t)BB * NH * NN * 16;
  ushort_t* VT = Kb + (size_t)BB * NH * NN * 16;
  ushort_t* Ab = VT + (size_t)BB * NH * NN * 16;
  ushort_t* Wb = Ab + (size_t)M_TOT * 64;
  ushort_t* Wqkv1 = Wb;
  ushort_t* Wo1   = Wb + 12288;
  ushort_t* W1_1  = Wb + 16384;
  ushort_t* W2_1  = Wb + 20480;
  ushort_t* Wqkv2 = Wb + 24576;
  ushort_t* Wo2   = Wb + 36864;
  ushort_t* W1_2  = Wb + 40960;
  ushort_t* W2_2  = Wb + 45056;
  ushort_t* Wmid  = Wb + 49152;

  cvtw_kernel<<<dim3(16, 9), 256, 0, stream>>>(
      SA1[2], SA1[4], SA1[8], SA1[10], SA2[2], SA2[4], SA2[8], SA2[10], w_mid, Wb);
  temb_kernel<<<BB, 64, 0, stream>>>(t_int, e1w, e1b, e2w, e2b, temb1, temb2);

  // SA1
  qkv_kernel<true><<<M_TOT / 64, 256, 0, stream>>>(
      nullptr, pos, w_in, b_in, temb1, X, SA1[0], SA1[1], Wqkv1, SA1[3], Qb, Kb, VT);
  attn_kernel<<<BB * NH * 16, 256, 0, stream>>>(Qb, Kb, VT, Ab);
  ffn_kernel<0><<<M_TOT / 64, 256, 0, stream>>>(
      Ab, X, Wo1, SA1[5], SA1[6], SA1[7], W1_1, SA1[9], W2_1, SA1[11],
      Wmid, b_mid, temb2, nullptr, nullptr, nullptr, X2);
  // SA2
  qkv_kernel<false><<<M_TOT / 64, 256, 0, stream>>>(
      X2, nullptr, nullptr, nullptr, nullptr, nullptr, SA2[0], SA2[1], Wqkv2, SA2[3], Qb, Kb, VT);
  attn_kernel<<<BB * NH * 16, 256, 0, stream>>>(Qb, Kb, VT, Ab);
  ffn_kernel<1><<<M_TOT / 64, 256, 0, stream>>>(
      Ab, X2, Wo2, SA2[5], SA2[6], SA2[7], W1_2, SA2[9], W2_2, SA2[11],
      nullptr, nullptr, nullptr, w_out, b_out, nmask, (float*)d_out);
}

// Round 4
// 130.569 us; speedup vs baseline: 10.6204x; 1.0774x over previous
//
#include <hip/hip_runtime.h>
#include <hip/hip_bf16.h>
#include <math.h>

// SimpleFC: B=16, N=1024, E=64, H=4, dh=16.
#define NH 4
#define EE 64
#define BB 16
#define NN 1024
#define M_TOT (BB * NN)
#define QSCALE 0.3606737602222409f   // 0.25 * log2(e)

typedef short bf16x4 __attribute__((ext_vector_type(4)));
typedef float f32x4 __attribute__((ext_vector_type(4)));
typedef unsigned short ushort_t;

// ---------- helpers ----------
__device__ __forceinline__ unsigned int cvt_pk_bf16(float a, float b) {
  unsigned int r;
  asm("v_cvt_pk_bf16_f32 %0, %1, %2" : "=v"(r) : "v"(a), "v"(b));
  return r;
}
__device__ __forceinline__ ushort_t f2bf(float v) {
  return (ushort_t)cvt_pk_bf16(v, v);
}
__device__ __forceinline__ bf16x4 pack4(float a, float b, float c, float d) {
  uint2 u; u.x = cvt_pk_bf16(a, b); u.y = cvt_pk_bf16(c, d);
  return __builtin_bit_cast(bf16x4, u);
}
__device__ __forceinline__ bf16x4 ldbf4(const ushort_t* p) {
  return __builtin_bit_cast(bf16x4, *reinterpret_cast<const uint2*>(p));
}

struct Frag { bf16x4 a[4]; };
__device__ __forceinline__ Frag ldA(const ushort_t* s, int row, int lg) {
  Frag f;
  #pragma unroll
  for (int kb = 0; kb < 4; ++kb) f.a[kb] = ldbf4(s + row * 68 + kb * 16 + 4 * lg);
  return f;
}
__device__ __forceinline__ f32x4 gemmW(const Frag& f, const ushort_t* W, int jcol, int lg) {
  f32x4 acc = {0.f, 0.f, 0.f, 0.f};
  const ushort_t* wb = W + jcol * 64 + 4 * lg;
  #pragma unroll
  for (int kb = 0; kb < 4; ++kb)
    acc = __builtin_amdgcn_mfma_f32_16x16x16bf16_1k(f.a[kb], ldbf4(wb + kb * 16), acc, 0, 0, 0);
  return acc;
}
// LN a 32x64 f32 LDS tile (stride 66) -> bf16 LDS tile (stride 68). 8 threads/row.
__device__ __forceinline__ void ln_stage(const float* s_src, ushort_t* s_dst,
    const float* __restrict__ g, const float* __restrict__ beta, int tid) {
  int r = tid >> 3, c0 = (tid & 7) * 8;
  float v[8];
  #pragma unroll
  for (int j = 0; j < 8; ++j) v[j] = s_src[r * 66 + c0 + j];
  float s = 0.f;
  #pragma unroll
  for (int j = 0; j < 8; ++j) s += v[j];
  s += __shfl_xor(s, 1); s += __shfl_xor(s, 2); s += __shfl_xor(s, 4);
  float mean = s * (1.f / EE);
  float qv = 0.f;
  #pragma unroll
  for (int j = 0; j < 8; ++j) { float d = v[j] - mean; qv += d * d; }
  qv += __shfl_xor(qv, 1); qv += __shfl_xor(qv, 2); qv += __shfl_xor(qv, 4);
  float rs = rsqrtf(qv * (1.f / EE) + 1e-5f);
  unsigned int* dst = (unsigned int*)(s_dst + r * 68 + c0);
  #pragma unroll
  for (int j = 0; j < 4; ++j) {
    float h0 = (v[2*j]   - mean) * rs * g[c0 + 2*j]   + beta[c0 + 2*j];
    float h1 = (v[2*j+1] - mean) * rs * g[c0 + 2*j+1] + beta[c0 + 2*j+1];
    dst[j] = cvt_pk_bf16(h0, h1);
  }
}

// ---------- prep: weight f32->bf16 (y<9) + timestep embedding (y==9) ----------
__global__ __launch_bounds__(256) void prep_kernel(
    const float* a0, const float* a1, const float* a2, const float* a3,
    const float* a4, const float* a5, const float* a6, const float* a7,
    const float* a8, ushort_t* __restrict__ dst,
    const float* __restrict__ t_int,
    const float* __restrict__ e1w, const float* __restrict__ e1b,
    const float* __restrict__ e2w, const float* __restrict__ e2b,
    float* __restrict__ temb1, float* __restrict__ temb2)
{
  if (blockIdx.y < 9) {
    const int off[9] = {0, 12288, 16384, 20480, 24576, 36864, 40960, 45056, 49152};
    const int sz[9]  = {12288, 4096, 4096, 4096, 12288, 4096, 4096, 4096, 4096};
    const float* srcs[9] = {a0, a1, a2, a3, a4, a5, a6, a7, a8};
    int s = blockIdx.y;
    const float* src = srcs[s];
    for (int i = blockIdx.x * 256 + threadIdx.x; i < sz[s]; i += 16 * 256)
      dst[off[s] + i] = f2bf(src[i]);
    return;
  }
  // temb: 16 x-blocks (one per batch), threads 0..63
  __shared__ float s_silu[EE];
  int b = blockIdx.x, e = threadIdx.x;
  if (e >= 64) return;
  float t = t_int[b];
  int i = e & 31;
  float inv_freq = powf(10000.f, -(float)(2 * i) / (float)EE);
  float ang = t * inv_freq;
  float ti = (e < 32) ? sinf(ang) : cosf(ang);
  s_silu[e] = ti / (1.f + expf(-ti));
  __syncthreads();
  float v1 = e1b[e], v2 = e2b[e];
  #pragma unroll 8
  for (int k = 0; k < EE; ++k) {
    float s = s_silu[k];
    v1 = fmaf(s, e1w[e * EE + k], v1);
    v2 = fmaf(s, e2w[e * EE + k], v2);
  }
  temb1[b * EE + e] = v1;
  temb2[b * EE + e] = v2;
}

// ---------- xinit + LN + QKV projection (SA1 entry). 32-row tile, col-split waves ----------
__global__ __launch_bounds__(256) void qkv1_kernel(
    const float* __restrict__ pos,
    const float* __restrict__ w_in, const float* __restrict__ b_in,
    const float* __restrict__ temb1, float* __restrict__ Xout,
    const float* __restrict__ g, const float* __restrict__ beta,
    const ushort_t* __restrict__ Wq, const float* __restrict__ bq,
    ushort_t* __restrict__ Qb, ushort_t* __restrict__ Kb, ushort_t* __restrict__ VT)
{
  __shared__ ushort_t s_h[32 * 68];
  const int tid = threadIdx.x;
  const int m0 = blockIdx.x * 32;
  const int b = m0 >> 10;
  const int r = tid >> 3, c0 = (tid & 7) * 8;
  float v[8];
  {
    const float* pr = pos + (size_t)(m0 + r) * 3;
    float p0 = pr[0], p1 = pr[1], p2 = pr[2];
    #pragma unroll
    for (int j = 0; j < 8; ++j) {
      int c = c0 + j;
      float t = b_in[c] + temb1[b * EE + c];
      t = fmaf(p0, w_in[c * 3 + 0], t);
      t = fmaf(p1, w_in[c * 3 + 1], t);
      t = fmaf(p2, w_in[c * 3 + 2], t);
      v[j] = t;
    }
    float4* xo = (float4*)(Xout + (size_t)(m0 + r) * 64 + c0);
    float4 t4a = {v[0], v[1], v[2], v[3]}, t4b = {v[4], v[5], v[6], v[7]};
    xo[0] = t4a; xo[1] = t4b;
  }
  // LN (8 threads/row)
  float s = 0.f;
  #pragma unroll
  for (int j = 0; j < 8; ++j) s += v[j];
  s += __shfl_xor(s, 1); s += __shfl_xor(s, 2); s += __shfl_xor(s, 4);
  float mean = s * (1.f / EE);
  float qv = 0.f;
  #pragma unroll
  for (int j = 0; j < 8; ++j) { float d = v[j] - mean; qv += d * d; }
  qv += __shfl_xor(qv, 1); qv += __shfl_xor(qv, 2); qv += __shfl_xor(qv, 4);
  float rs = rsqrtf(qv * (1.f / EE) + 1e-5f);
  {
    unsigned int* sh = (unsigned int*)&s_h[r * 68 + c0];
    #pragma unroll
    for (int j = 0; j < 4; ++j) {
      float h0 = (v[2*j]   - mean) * rs * g[c0 + 2*j]   + beta[c0 + 2*j];
      float h1 = (v[2*j+1] - mean) * rs * g[c0 + 2*j+1] + beta[c0 + 2*j+1];
      sh[j] = cvt_pk_bf16(h0, h1);
    }
  }
  __syncthreads();
  const int w = tid >> 6, l = tid & 63, lr = l & 15, lg = l >> 4;
  const int rowoff = (w & 1) * 16, jt0 = (w >> 1) * 6;
  Frag af = ldA(s_h, rowoff + lr, lg);
  const int q0s = (m0 & 1023) + rowoff + 4 * lg;
  #pragma unroll
  for (int jtl = 0; jtl < 6; ++jtl) {
    int jt = jt0 + jtl;
    f32x4 acc = gemmW(af, Wq, jt * 16 + lr, lg);
    float bias = bq[jt * 16 + lr];
    if (jt < 4) {
      ushort_t* dst = Qb + ((size_t)(b * NH + jt) * NN + q0s) * 16 + lr;
      #pragma unroll
      for (int rr = 0; rr < 4; ++rr) dst[rr * 16] = f2bf((acc[rr] + bias) * QSCALE);
    } else if (jt < 8) {
      ushort_t* dst = Kb + ((size_t)(b * NH + jt - 4) * NN + q0s) * 16 + lr;
      #pragma unroll
      for (int rr = 0; rr < 4; ++rr) dst[rr * 16] = f2bf(acc[rr] + bias);
    } else {
      ushort_t* dst = VT + ((size_t)(b * NH + jt - 8) * 16 + lr) * NN + q0s;
      bf16x4 pv = pack4(acc[0] + bias, acc[1] + bias, acc[2] + bias, acc[3] + bias);
      *reinterpret_cast<uint2*>(dst) = __builtin_bit_cast(uint2, pv);
    }
  }
}

// ---------- MFMA flash attention, split-KV (additive partials; no-max exp2 softmax) ----------
// grid = 64 bh * 32 qblk = 2048 blocks; block = 4 waves: (pair = q-subtile, kvh = kv half)
__global__ __launch_bounds__(256) void attn_kernel(
    const ushort_t* __restrict__ Qb, const ushort_t* __restrict__ Kb,
    const ushort_t* __restrict__ VT, ushort_t* __restrict__ Ab)
{
  __shared__ float s_o[2][64][5];
  const int tid = threadIdx.x, w = tid >> 6, l = tid & 63, lr = l & 15, lg = l >> 4;
  const int pair = w >> 1, kvh = w & 1;
  const int blk = blockIdx.x, bh = blk >> 5, qblk = blk & 31;
  const int q0 = qblk * 32 + pair * 16;
  bf16x4 qf = ldbf4(Qb + ((size_t)bh * NN + q0 + lr) * 16 + 4 * lg);
  const ushort_t* kp = Kb + (size_t)bh * NN * 16 + (kvh * 512 + lr) * 16 + 4 * lg;
  const ushort_t* vp = VT + ((size_t)bh * 16 + lr) * NN + kvh * 512 + 4 * lg;
  f32x4 o = {0.f, 0.f, 0.f, 0.f};
  float psum = 0.f;
  #pragma unroll 4
  for (int c = 0; c < 32; ++c) {
    bf16x4 kf = ldbf4(kp + c * 256);
    bf16x4 vf = ldbf4(vp + c * 16);
    f32x4 z = {0.f, 0.f, 0.f, 0.f};
    f32x4 st = __builtin_amdgcn_mfma_f32_16x16x16bf16_1k(kf, qf, z, 0, 0, 0);
    float p0 = __builtin_amdgcn_exp2f(st[0]);
    float p1 = __builtin_amdgcn_exp2f(st[1]);
    float p2 = __builtin_amdgcn_exp2f(st[2]);
    float p3 = __builtin_amdgcn_exp2f(st[3]);
    psum += (p0 + p1) + (p2 + p3);
    bf16x4 pf = pack4(p0, p1, p2, p3);
    o = __builtin_amdgcn_mfma_f32_16x16x16bf16_1k(vf, pf, o, 0, 0, 0);
  }
  if (kvh == 1) {
    #pragma unroll
    for (int rr = 0; rr < 4; ++rr) s_o[pair][l][rr] = o[rr];
    s_o[pair][l][4] = psum;
  }
  __syncthreads();
  if (kvh == 0) {
    #pragma unroll
    for (int rr = 0; rr < 4; ++rr) o[rr] += s_o[pair][l][rr];
    psum += s_o[pair][l][4];
    psum += __shfl_xor(psum, 16);
    psum += __shfl_xor(psum, 32);
    float inv = 1.f / psum;
    const int b = bh >> 2, h = bh & 3;
    ushort_t* dst = Ab + ((size_t)b * NN + q0 + lr) * 64 + h * 16 + 4 * lg;
    bf16x4 ov = pack4(o[0] * inv, o[1] * inv, o[2] * inv, o[3] * inv);
    *reinterpret_cast<uint2*>(dst) = __builtin_bit_cast(uint2, ov);
  }
}

// ---------- SA1 tail: out-proj+res -> LN -> gelu-F1 -> F2+res -> mid-linear -> LN -> QKV(SA2) ----------
__global__ __launch_bounds__(256) void ffnq_kernel(
    const ushort_t* __restrict__ Ab, const float* __restrict__ Xres,
    const ushort_t* __restrict__ Wo, const float* __restrict__ bo,
    const float* __restrict__ g, const float* __restrict__ beta,
    const ushort_t* __restrict__ W1, const float* __restrict__ b1,
    const ushort_t* __restrict__ W2, const float* __restrict__ b2,
    const ushort_t* __restrict__ Wt, const float* __restrict__ bt,
    const float* __restrict__ temb2,
    const float* __restrict__ g2, const float* __restrict__ beta2,
    const ushort_t* __restrict__ Wq, const float* __restrict__ bq,
    float* __restrict__ X2,
    ushort_t* __restrict__ Qb, ushort_t* __restrict__ Kb, ushort_t* __restrict__ VT)
{
  __shared__ ushort_t s_b1[32 * 68];
  __shared__ ushort_t s_b2[32 * 68];
  __shared__ float s_av[32 * 66];
  __shared__ float s_rs[32 * 66];
  const int tid = threadIdx.x;
  const int m0 = blockIdx.x * 32, b = m0 >> 10;
  const int r = tid >> 3, c0 = (tid & 7) * 8;
  {
    const uint2* ai = (const uint2*)(Ab + (size_t)(m0 + r) * 64 + c0);
    uint2* ao = (uint2*)&s_b1[r * 68 + c0];
    ao[0] = ai[0]; ao[1] = ai[1];
    const float4* xi = (const float4*)(Xres + (size_t)(m0 + r) * 64 + c0);
    float4* xo = (float4*)&s_rs[r * 66 + c0];
    xo[0] = xi[0]; xo[1] = xi[1];
  }
  __syncthreads();
  const int w = tid >> 6, l = tid & 63, lr = l & 15, lg = l >> 4;
  const int rowoff = (w & 1) * 16, jt0 = (w >> 1) * 2;
  // G1: av = A @ Wo^T + bo + Xres -> s_av
  {
    Frag af = ldA(s_b1, rowoff + lr, lg);
    #pragma unroll
    for (int jtl = 0; jtl < 2; ++jtl) {
      int jt = jt0 + jtl;
      f32x4 acc = gemmW(af, Wo, jt * 16 + lr, lg);
      float bias = bo[jt * 16 + lr];
      #pragma unroll
      for (int rr = 0; rr < 4; ++rr) {
        int m = rowoff + 4 * lg + rr;
        s_av[m * 66 + jt * 16 + lr] = acc[rr] + bias + s_rs[m * 66 + jt * 16 + lr];
      }
    }
  }
  __syncthreads();
  ln_stage(s_av, s_b1, g, beta, tid);
  __syncthreads();
  // G2: gelu(h @ W1^T + b1) -> s_b2
  {
    Frag af = ldA(s_b1, rowoff + lr, lg);
    #pragma unroll
    for (int jtl = 0; jtl < 2; ++jtl) {
      int jt = jt0 + jtl;
      f32x4 acc = gemmW(af, W1, jt * 16 + lr, lg);
      float bias = b1[jt * 16 + lr];
      #pragma unroll
      for (int rr = 0; rr < 4; ++rr) {
        float t = acc[rr] + bias;
        t = 0.5f * t * (1.f + erff(t * 0.70710678118f));
        s_b2[(rowoff + 4 * lg + rr) * 68 + jt * 16 + lr] = f2bf(t);
      }
    }
  }
  __syncthreads();
  // G3: xnew = h1 @ W2^T + b2 + av; store relu(xnew) bf16 -> s_b1
  {
    Frag af = ldA(s_b2, rowoff + lr, lg);
    #pragma unroll
    for (int jtl = 0; jtl < 2; ++jtl) {
      int jt = jt0 + jtl;
      f32x4 acc = gemmW(af, W2, jt * 16 + lr, lg);
      float bias = b2[jt * 16 + lr];
      #pragma unroll
      for (int rr = 0; rr < 4; ++rr) {
        int m = rowoff + 4 * lg + rr;
        float sa = acc[rr] + bias + s_av[m * 66 + jt * 16 + lr];
        s_b1[m * 68 + jt * 16 + lr] = f2bf(fmaxf(sa, 0.f));
      }
    }
  }
  __syncthreads();
  // G4: X2 = relu(xnew) @ Wmid^T + bmid + temb2 -> global + s_av
  {
    Frag af = ldA(s_b1, rowoff + lr, lg);
    #pragma unroll
    for (int jtl = 0; jtl < 2; ++jtl) {
      int jt = jt0 + jtl;
      f32x4 acc = gemmW(af, Wt, jt * 16 + lr, lg);
      float bias = bt[jt * 16 + lr] + temb2[b * EE + jt * 16 + lr];
      #pragma unroll
      for (int rr = 0; rr < 4; ++rr) {
        int m = rowoff + 4 * lg + rr;
        float x2 = acc[rr] + bias;
        s_av[m * 66 + jt * 16 + lr] = x2;
        X2[(size_t)(m0 + m) * 64 + jt * 16 + lr] = x2;
      }
    }
  }
  __syncthreads();
  ln_stage(s_av, s_b1, g2, beta2, tid);
  __syncthreads();
  // G5: QKV projection for SA2 (192 cols; 6 tiles per wave)
  {
    Frag af = ldA(s_b1, rowoff + lr, lg);
    const int jq0 = (w >> 1) * 6;
    const int q0s = (m0 & 1023) + rowoff + 4 * lg;
    #pragma unroll
    for (int jtl = 0; jtl < 6; ++jtl) {
      int jt = jq0 + jtl;
      f32x4 acc = gemmW(af, Wq, jt * 16 + lr, lg);
      float bias = bq[jt * 16 + lr];
      if (jt < 4) {
        ushort_t* dst = Qb + ((size_t)(b * NH + jt) * NN + q0s) * 16 + lr;
        #pragma unroll
        for (int rr = 0; rr < 4; ++rr) dst[rr * 16] = f2bf((acc[rr] + bias) * QSCALE);
      } else if (jt < 8) {
        ushort_t* dst = Kb + ((size_t)(b * NH + jt - 4) * NN + q0s) * 16 + lr;
        #pragma unroll
        for (int rr = 0; rr < 4; ++rr) dst[rr * 16] = f2bf(acc[rr] + bias);
      } else {
        ushort_t* dst = VT + ((size_t)(b * NH + jt - 8) * 16 + lr) * NN + q0s;
        bf16x4 pv = pack4(acc[0] + bias, acc[1] + bias, acc[2] + bias, acc[3] + bias);
        *reinterpret_cast<uint2*>(dst) = __builtin_bit_cast(uint2, pv);
      }
    }
  }
}

// ---------- SA2 tail: out-proj+res -> LN -> gelu-F1 -> F2+res -> final 3-col * mask ----------
__global__ __launch_bounds__(256) void ffn_final_kernel(
    const ushort_t* __restrict__ Ab, const float* __restrict__ Xres,
    const ushort_t* __restrict__ Wo, const float* __restrict__ bo,
    const float* __restrict__ g, const float* __restrict__ beta,
    const ushort_t* __restrict__ W1, const float* __restrict__ b1,
    const ushort_t* __restrict__ W2, const float* __restrict__ b2,
    const float* __restrict__ wout3, const float* __restrict__ bout3,
    const float* __restrict__ mask,
    float* __restrict__ Out)
{
  __shared__ ushort_t s_b1[32 * 68];
  __shared__ ushort_t s_b2[32 * 68];
  __shared__ float s_av[32 * 66];
  __shared__ float s_rs[32 * 66];
  const int tid = threadIdx.x;
  const int m0 = blockIdx.x * 32;
  const int r = tid >> 3, c0 = (tid & 7) * 8;
  {
    const uint2* ai = (const uint2*)(Ab + (size_t)(m0 + r) * 64 + c0);
    uint2* ao = (uint2*)&s_b1[r * 68 + c0];
    ao[0] = ai[0]; ao[1] = ai[1];
    const float4* xi = (const float4*)(Xres + (size_t)(m0 + r) * 64 + c0);
    float4* xo = (float4*)&s_rs[r * 66 + c0];
    xo[0] = xi[0]; xo[1] = xi[1];
  }
  __syncthreads();
  const int w = tid >> 6, l = tid & 63, lr = l & 15, lg = l >> 4;
  const int rowoff = (w & 1) * 16, jt0 = (w >> 1) * 2;
  {
    Frag af = ldA(s_b1, rowoff + lr, lg);
    #pragma unroll
    for (int jtl = 0; jtl < 2; ++jtl) {
      int jt = jt0 + jtl;
      f32x4 acc = gemmW(af, Wo, jt * 16 + lr, lg);
      float bias = bo[jt * 16 + lr];
      #pragma unroll
      for (int rr = 0; rr < 4; ++rr) {
        int m = rowoff + 4 * lg + rr;
        s_av[m * 66 + jt * 16 + lr] = acc[rr] + bias + s_rs[m * 66 + jt * 16 + lr];
      }
    }
  }
  __syncthreads();
  ln_stage(s_av, s_b1, g, beta, tid);
  __syncthreads();
  {
    Frag af = ldA(s_b1, rowoff + lr, lg);
    #pragma unroll
    for (int jtl = 0; jtl < 2; ++jtl) {
      int jt = jt0 + jtl;
      f32x4 acc = gemmW(af, W1, jt * 16 + lr, lg);
      float bias = b1[jt * 16 + lr];
      #pragma unroll
      for (int rr = 0; rr < 4; ++rr) {
        float t = acc[rr] + bias;
        t = 0.5f * t * (1.f + erff(t * 0.70710678118f));
        s_b2[(rowoff + 4 * lg + rr) * 68 + jt * 16 + lr] = f2bf(t);
      }
    }
  }
  __syncthreads();
  {
    Frag af = ldA(s_b2, rowoff + lr, lg);
    #pragma unroll
    for (int jtl = 0; jtl < 2; ++jtl) {
      int jt = jt0 + jtl;
      f32x4 acc = gemmW(af, W2, jt * 16 + lr, lg);
      float bias = b2[jt * 16 + lr];
      #pragma unroll
      for (int rr = 0; rr < 4; ++rr) {
        int m = rowoff + 4 * lg + rr;
        s_rs[m * 66 + jt * 16 + lr] = acc[rr] + bias + s_av[m * 66 + jt * 16 + lr];
      }
    }
  }
  __syncthreads();
  if (tid < 96) {
    int row = tid / 3, c = tid - row * 3;
    float acc = bout3[c];
    #pragma unroll 8
    for (int k = 0; k < 64; ++k)
      acc = fmaf(fmaxf(s_rs[row * 66 + k], 0.f), wout3[c * 64 + k], acc);
    Out[(size_t)(m0 + row) * 3 + c] = acc * mask[m0 + row];
  }
}

// ---------- host ----------
extern "C" void kernel_launch(void* const* d_in, const int* in_sizes, int n_in,
                              void* d_out, int out_size, void* d_ws, size_t ws_size,
                              hipStream_t stream)
{
  const float* pos    = (const float*)d_in[0];
  const float* t_int  = (const float*)d_in[1];
  const float* nmask  = (const float*)d_in[2];
  const float* w_in   = (const float*)d_in[3];
  const float* b_in   = (const float*)d_in[4];
  const float* w_mid  = (const float*)d_in[5];
  const float* b_mid  = (const float*)d_in[6];
  const float* w_out  = (const float*)d_in[7];
  const float* b_out  = (const float*)d_in[8];
  const float* e1w    = (const float*)d_in[9];
  const float* e1b    = (const float*)d_in[10];
  const float* e2w    = (const float*)d_in[11];
  const float* e2b    = (const float*)d_in[12];
  const float* const* SA1 = (const float* const*)(d_in + 13);
  const float* const* SA2 = (const float* const*)(d_in + 25);

  float* ws    = (float*)d_ws;
  float* temb1 = ws;
  float* temb2 = ws + 1024;
  float* X     = ws + 2048;
  float* X2    = X + (size_t)M_TOT * 64;
  ushort_t* ub = (ushort_t*)(X2 + (size_t)M_TOT * 64);
  ushort_t* Qb = ub;
  ushort_t* Kb = Qb + (size_t)BB * NH * NN * 16;
  ushort_t* VT = Kb + (size_t)BB * NH * NN * 16;
  ushort_t* Ab = VT + (size_t)BB * NH * NN * 16;
  ushort_t* Wb = Ab + (size_t)M_TOT * 64;
  ushort_t* Wqkv1 = Wb;
  ushort_t* Wo1   = Wb + 12288;
  ushort_t* W1_1  = Wb + 16384;
  ushort_t* W2_1  = Wb + 20480;
  ushort_t* Wqkv2 = Wb + 24576;
  ushort_t* Wo2   = Wb + 36864;
  ushort_t* W1_2  = Wb + 40960;
  ushort_t* W2_2  = Wb + 45056;
  ushort_t* Wmid  = Wb + 49152;

  prep_kernel<<<dim3(16, 10), 256, 0, stream>>>(
      SA1[2], SA1[4], SA1[8], SA1[10], SA2[2], SA2[4], SA2[8], SA2[10], w_mid, Wb,
      t_int, e1w, e1b, e2w, e2b, temb1, temb2);

  qkv1_kernel<<<M_TOT / 32, 256, 0, stream>>>(
      pos, w_in, b_in, temb1, X, SA1[0], SA1[1], Wqkv1, SA1[3], Qb, Kb, VT);
  attn_kernel<<<BB * NH * 32, 256, 0, stream>>>(Qb, Kb, VT, Ab);
  ffnq_kernel<<<M_TOT / 32, 256, 0, stream>>>(
      Ab, X, Wo1, SA1[5], SA1[6], SA1[7], W1_1, SA1[9], W2_1, SA1[11],
      Wmid, b_mid, temb2, SA2[0], SA2[1], Wqkv2, SA2[3], X2, Qb, Kb, VT);
  attn_kernel<<<BB * NH * 32, 256, 0, stream>>>(Qb, Kb, VT, Ab);
  ffn_final_kernel<<<M_TOT / 32, 256, 0, stream>>>(
      Ab, X2, Wo2, SA2[5], SA2[6], SA2[7], W1_2, SA2[9], W2_2, SA2[11],
      w_out, b_out, nmask, (float*)d_out);
}

// Round 7
// 125.812 us; speedup vs baseline: 11.0219x; 1.0378x over previous
//
#include <hip/hip_runtime.h>
#include <hip/hip_bf16.h>
#include <math.h>

// SimpleFC: B=16, N=1024, E=64, H=4, dh=16.
#define NH 4
#define EE 64
#define BB 16
#define NN 1024
#define M_TOT (BB * NN)
#define QSCALE 0.3606737602222409f   // 0.25 * log2(e)

typedef short bf16x4 __attribute__((ext_vector_type(4)));
typedef float f32x4 __attribute__((ext_vector_type(4)));
typedef unsigned short ushort_t;

// ---------- helpers (R4-proven) ----------
__device__ __forceinline__ unsigned int cvt_pk_bf16(float a, float b) {
  unsigned int r;
  asm("v_cvt_pk_bf16_f32 %0, %1, %2" : "=v"(r) : "v"(a), "v"(b));
  return r;
}
__device__ __forceinline__ ushort_t f2bf(float v) { return (ushort_t)cvt_pk_bf16(v, v); }
__device__ __forceinline__ bf16x4 pack4(float a, float b, float c, float d) {
  uint2 u; u.x = cvt_pk_bf16(a, b); u.y = cvt_pk_bf16(c, d);
  return __builtin_bit_cast(bf16x4, u);
}
__device__ __forceinline__ bf16x4 ldbf4(const ushort_t* p) {
  return __builtin_bit_cast(bf16x4, *reinterpret_cast<const uint2*>(p));
}

struct Frag { bf16x4 a[4]; };
__device__ __forceinline__ Frag ldA(const ushort_t* s, int row, int lg) {
  Frag f;
  #pragma unroll
  for (int kb = 0; kb < 4; ++kb) f.a[kb] = ldbf4(s + row * 68 + kb * 16 + 4 * lg);
  return f;
}
__device__ __forceinline__ f32x4 gemmW(const Frag& f, const ushort_t* W, int jcol, int lg) {
  f32x4 acc = {0.f, 0.f, 0.f, 0.f};
  const ushort_t* wb = W + jcol * 64 + 4 * lg;
  #pragma unroll
  for (int kb = 0; kb < 4; ++kb)
    acc = __builtin_amdgcn_mfma_f32_16x16x16bf16_1k(f.a[kb], ldbf4(wb + kb * 16), acc, 0, 0, 0);
  return acc;
}
// LN a 32x64 f32 LDS tile (stride 66) -> bf16 LDS tile (stride 68). 8 threads/row. (R4-proven)
__device__ __forceinline__ void ln_stage(const float* s_src, ushort_t* s_dst,
    const float* __restrict__ g, const float* __restrict__ beta, int tid) {
  int r = tid >> 3, c0 = (tid & 7) * 8;
  float v[8];
  #pragma unroll
  for (int j = 0; j < 8; ++j) v[j] = s_src[r * 66 + c0 + j];
  float s = 0.f;
  #pragma unroll
  for (int j = 0; j < 8; ++j) s += v[j];
  s += __shfl_xor(s, 1); s += __shfl_xor(s, 2); s += __shfl_xor(s, 4);
  float mean = s * (1.f / EE);
  float qv = 0.f;
  #pragma unroll
  for (int j = 0; j < 8; ++j) { float d = v[j] - mean; qv += d * d; }
  qv += __shfl_xor(qv, 1); qv += __shfl_xor(qv, 2); qv += __shfl_xor(qv, 4);
  float rs = rsqrtf(qv * (1.f / EE) + 1e-5f);
  unsigned int* dst = (unsigned int*)(s_dst + r * 68 + c0);
  #pragma unroll
  for (int j = 0; j < 4; ++j) {
    float h0 = (v[2*j]   - mean) * rs * g[c0 + 2*j]   + beta[c0 + 2*j];
    float h1 = (v[2*j+1] - mean) * rs * g[c0 + 2*j+1] + beta[c0 + 2*j+1];
    dst[j] = cvt_pk_bf16(h0, h1);
  }
}

// ---------- prep: weight f32->bf16 (y<9) + timestep embedding (y==9) ----------
__global__ __launch_bounds__(256) void prep_kernel(
    const float* a0, const float* a1, const float* a2, const float* a3,
    const float* a4, const float* a5, const float* a6, const float* a7,
    const float* a8, ushort_t* __restrict__ dst,
    const float* __restrict__ t_int,
    const float* __restrict__ e1w, const float* __restrict__ e1b,
    const float* __restrict__ e2w, const float* __restrict__ e2b,
    float* __restrict__ temb1, float* __restrict__ temb2)
{
  if (blockIdx.y < 9) {
    const int off[9] = {0, 12288, 16384, 20480, 24576, 36864, 40960, 45056, 49152};
    const int sz[9]  = {12288, 4096, 4096, 4096, 12288, 4096, 4096, 4096, 4096};
    const float* srcs[9] = {a0, a1, a2, a3, a4, a5, a6, a7, a8};
    int s = blockIdx.y;
    const float* src = srcs[s];
    for (int i = blockIdx.x * 256 + threadIdx.x; i < sz[s]; i += 16 * 256)
      dst[off[s] + i] = f2bf(src[i]);
    return;
  }
  __shared__ float s_silu[EE];
  int b = blockIdx.x, e = threadIdx.x;
  if (e >= 64) return;
  float t = t_int[b];
  int i = e & 31;
  float inv_freq = powf(10000.f, -(float)(2 * i) / (float)EE);
  float ang = t * inv_freq;
  float ti = (e < 32) ? sinf(ang) : cosf(ang);
  s_silu[e] = ti / (1.f + expf(-ti));
  __syncthreads();
  float v1 = e1b[e], v2 = e2b[e];
  #pragma unroll 8
  for (int k = 0; k < EE; ++k) {
    float s = s_silu[k];
    v1 = fmaf(s, e1w[e * EE + k], v1);
    v2 = fmaf(s, e2w[e * EE + k], v2);
  }
  temb1[b * EE + e] = v1;
  temb2[b * EE + e] = v2;
}

// ---------- xinit + LN + QKV projection (SA1 entry). 32-row tile, col-split waves ----------
__global__ __launch_bounds__(256) void qkv1_kernel(
    const float* __restrict__ pos,
    const float* __restrict__ w_in, const float* __restrict__ b_in,
    const float* __restrict__ temb1, float* __restrict__ Xout,
    const float* __restrict__ g, const float* __restrict__ beta,
    const ushort_t* __restrict__ Wq, const float* __restrict__ bq,
    ushort_t* __restrict__ Qb, ushort_t* __restrict__ Kb, ushort_t* __restrict__ VT)
{
  __shared__ ushort_t s_h[32 * 68];
  const int tid = threadIdx.x;
  const int m0 = blockIdx.x * 32;
  const int b = m0 >> 10;
  const int r = tid >> 3, c0 = (tid & 7) * 8;
  float v[8];
  {
    const float* pr = pos + (size_t)(m0 + r) * 3;
    float p0 = pr[0], p1 = pr[1], p2 = pr[2];
    #pragma unroll
    for (int j = 0; j < 8; ++j) {
      int c = c0 + j;
      float t = b_in[c] + temb1[b * EE + c];
      t = fmaf(p0, w_in[c * 3 + 0], t);
      t = fmaf(p1, w_in[c * 3 + 1], t);
      t = fmaf(p2, w_in[c * 3 + 2], t);
      v[j] = t;
    }
    float4* xo = (float4*)(Xout + (size_t)(m0 + r) * 64 + c0);
    float4 t4a = {v[0], v[1], v[2], v[3]}, t4b = {v[4], v[5], v[6], v[7]};
    xo[0] = t4a; xo[1] = t4b;
  }
  float s = 0.f;
  #pragma unroll
  for (int j = 0; j < 8; ++j) s += v[j];
  s += __shfl_xor(s, 1); s += __shfl_xor(s, 2); s += __shfl_xor(s, 4);
  float mean = s * (1.f / EE);
  float qv = 0.f;
  #pragma unroll
  for (int j = 0; j < 8; ++j) { float d = v[j] - mean; qv += d * d; }
  qv += __shfl_xor(qv, 1); qv += __shfl_xor(qv, 2); qv += __shfl_xor(qv, 4);
  float rs = rsqrtf(qv * (1.f / EE) + 1e-5f);
  {
    unsigned int* sh = (unsigned int*)&s_h[r * 68 + c0];
    #pragma unroll
    for (int j = 0; j < 4; ++j) {
      float h0 = (v[2*j]   - mean) * rs * g[c0 + 2*j]   + beta[c0 + 2*j];
      float h1 = (v[2*j+1] - mean) * rs * g[c0 + 2*j+1] + beta[c0 + 2*j+1];
      sh[j] = cvt_pk_bf16(h0, h1);
    }
  }
  __syncthreads();
  const int w = tid >> 6, l = tid & 63, lr = l & 15, lg = l >> 4;
  const int rowoff = (w & 1) * 16, jt0 = (w >> 1) * 6;
  Frag af = ldA(s_h, rowoff + lr, lg);
  const int q0s = (m0 & 1023) + rowoff + 4 * lg;
  #pragma unroll
  for (int jtl = 0; jtl < 6; ++jtl) {
    int jt = jt0 + jtl;
    f32x4 acc = gemmW(af, Wq, jt * 16 + lr, lg);
    float bias = bq[jt * 16 + lr];
    if (jt < 4) {
      ushort_t* dst = Qb + ((size_t)(b * NH + jt) * NN + q0s) * 16 + lr;
      #pragma unroll
      for (int rr = 0; rr < 4; ++rr) dst[rr * 16] = f2bf((acc[rr] + bias) * QSCALE);
    } else if (jt < 8) {
      ushort_t* dst = Kb + ((size_t)(b * NH + jt - 4) * NN + q0s) * 16 + lr;
      #pragma unroll
      for (int rr = 0; rr < 4; ++rr) dst[rr * 16] = f2bf(acc[rr] + bias);
    } else {
      ushort_t* dst = VT + ((size_t)(b * NH + jt - 8) * 16 + lr) * NN + q0s;
      bf16x4 pv = pack4(acc[0] + bias, acc[1] + bias, acc[2] + bias, acc[3] + bias);
      *reinterpret_cast<uint2*>(dst) = __builtin_bit_cast(uint2, pv);
    }
  }
}

// ---------- MFMA flash attention, split-KV (additive partials; no-max exp2 softmax) ----------
// grid = 64 bh * 32 qblk = 2048 blocks; block = 4 waves: (pair = q-subtile, kvh = kv half)
// XCD swizzle (T1): grid 2048 = 8 * 256, bijective remap groups consecutive work on one XCD
// so the 32 q-blocks sharing one (b,h)'s 64KB K/V land on the same L2.
__global__ __launch_bounds__(256) void attn_kernel(
    const ushort_t* __restrict__ Qb, const ushort_t* __restrict__ Kb,
    const ushort_t* __restrict__ VT, ushort_t* __restrict__ Ab)
{
  __shared__ float s_o[2][64][5];
  const int tid = threadIdx.x, w = tid >> 6, l = tid & 63, lr = l & 15, lg = l >> 4;
  const int pair = w >> 1, kvh = w & 1;
  const int blk = ((blockIdx.x & 7) << 8) | (blockIdx.x >> 3);  // XCD-aware bijection
  const int bh = blk >> 5, qblk = blk & 31;
  const int q0 = qblk * 32 + pair * 16;
  bf16x4 qf = ldbf4(Qb + ((size_t)bh * NN + q0 + lr) * 16 + 4 * lg);
  const ushort_t* kp = Kb + (size_t)bh * NN * 16 + (kvh * 512 + lr) * 16 + 4 * lg;
  const ushort_t* vp = VT + ((size_t)bh * 16 + lr) * NN + kvh * 512 + 4 * lg;
  f32x4 o = {0.f, 0.f, 0.f, 0.f};
  float psum = 0.f;
  #pragma unroll 8
  for (int c = 0; c < 32; ++c) {
    bf16x4 kf = ldbf4(kp + c * 256);
    bf16x4 vf = ldbf4(vp + c * 16);
    f32x4 z = {0.f, 0.f, 0.f, 0.f};
    f32x4 st = __builtin_amdgcn_mfma_f32_16x16x16bf16_1k(kf, qf, z, 0, 0, 0);
    float p0 = __builtin_amdgcn_exp2f(st[0]);
    float p1 = __builtin_amdgcn_exp2f(st[1]);
    float p2 = __builtin_amdgcn_exp2f(st[2]);
    float p3 = __builtin_amdgcn_exp2f(st[3]);
    psum += (p0 + p1) + (p2 + p3);
    bf16x4 pf = pack4(p0, p1, p2, p3);
    o = __builtin_amdgcn_mfma_f32_16x16x16bf16_1k(vf, pf, o, 0, 0, 0);
  }
  if (kvh == 1) {
    #pragma unroll
    for (int rr = 0; rr < 4; ++rr) s_o[pair][l][rr] = o[rr];
    s_o[pair][l][4] = psum;
  }
  __syncthreads();
  if (kvh == 0) {
    #pragma unroll
    for (int rr = 0; rr < 4; ++rr) o[rr] += s_o[pair][l][rr];
    psum += s_o[pair][l][4];
    psum += __shfl_xor(psum, 16);
    psum += __shfl_xor(psum, 32);
    float inv = 1.f / psum;
    const int b = bh >> 2, h = bh & 3;
    ushort_t* dst = Ab + ((size_t)b * NN + q0 + lr) * 64 + h * 16 + 4 * lg;
    bf16x4 ov = pack4(o[0] * inv, o[1] * inv, o[2] * inv, o[3] * inv);
    *reinterpret_cast<uint2*>(dst) = __builtin_bit_cast(uint2, ov);
  }
}

// ---------- SA1 tail: out-proj + res -> LN -> gelu-F1 -> F2+res -> mid-linear -> LN -> QKV(SA2) ----------
__global__ __launch_bounds__(256) void ffnq_kernel(
    const ushort_t* __restrict__ Ab, const float* __restrict__ Xres,
    const ushort_t* __restrict__ Wo, const float* __restrict__ bo,
    const float* __restrict__ g, const float* __restrict__ beta,
    const ushort_t* __restrict__ W1, const float* __restrict__ b1,
    const ushort_t* __restrict__ W2, const float* __restrict__ b2,
    const ushort_t* __restrict__ Wt, const float* __restrict__ bt,
    const float* __restrict__ temb2,
    const float* __restrict__ g2, const float* __restrict__ beta2,
    const ushort_t* __restrict__ Wq, const float* __restrict__ bq,
    float* __restrict__ X2,
    ushort_t* __restrict__ Qb, ushort_t* __restrict__ Kb, ushort_t* __restrict__ VT)
{
  __shared__ ushort_t s_b1[32 * 68];
  __shared__ ushort_t s_b2[32 * 68];
  __shared__ float s_av[32 * 66];
  __shared__ float s_rs[32 * 66];
  const int tid = threadIdx.x;
  const int m0 = blockIdx.x * 32, b = m0 >> 10;
  const int r = tid >> 3, c0 = (tid & 7) * 8;
  {
    const uint2* ai = (const uint2*)(Ab + (size_t)(m0 + r) * 64 + c0);
    uint2* ao = (uint2*)&s_b1[r * 68 + c0];
    ao[0] = ai[0]; ao[1] = ai[1];
    const float4* xi = (const float4*)(Xres + (size_t)(m0 + r) * 64 + c0);
    float4* xo = (float4*)&s_rs[r * 66 + c0];
    xo[0] = xi[0]; xo[1] = xi[1];
  }
  __syncthreads();
  const int w = tid >> 6, l = tid & 63, lr = l & 15, lg = l >> 4;
  const int rowoff = (w & 1) * 16, jt0 = (w >> 1) * 2;
  // G1: av = A @ Wo^T + bo + Xres -> s_av
  {
    Frag af = ldA(s_b1, rowoff + lr, lg);
    #pragma unroll
    for (int jtl = 0; jtl < 2; ++jtl) {
      int jt = jt0 + jtl;
      f32x4 acc = gemmW(af, Wo, jt * 16 + lr, lg);
      float bias = bo[jt * 16 + lr];
      #pragma unroll
      for (int rr = 0; rr < 4; ++rr) {
        int m = rowoff + 4 * lg + rr;
        s_av[m * 66 + jt * 16 + lr] = acc[rr] + bias + s_rs[m * 66 + jt * 16 + lr];
      }
    }
  }
  __syncthreads();
  ln_stage(s_av, s_b1, g, beta, tid);
  __syncthreads();
  // G2: gelu(h @ W1^T + b1) -> s_b2
  {
    Frag af = ldA(s_b1, rowoff + lr, lg);
    #pragma unroll
    for (int jtl = 0; jtl < 2; ++jtl) {
      int jt = jt0 + jtl;
      f32x4 acc = gemmW(af, W1, jt * 16 + lr, lg);
      float bias = b1[jt * 16 + lr];
      #pragma unroll
      for (int rr = 0; rr < 4; ++rr) {
        float t = acc[rr] + bias;
        t = 0.5f * t * (1.f + erff(t * 0.70710678118f));
        s_b2[(rowoff + 4 * lg + rr) * 68 + jt * 16 + lr] = f2bf(t);
      }
    }
  }
  __syncthreads();
  // G3: xnew = h1 @ W2^T + b2 + av; store relu(xnew) bf16 -> s_b1
  {
    Frag af = ldA(s_b2, rowoff + lr, lg);
    #pragma unroll
    for (int jtl = 0; jtl < 2; ++jtl) {
      int jt = jt0 + jtl;
      f32x4 acc = gemmW(af, W2, jt * 16 + lr, lg);
      float bias = b2[jt * 16 + lr];
      #pragma unroll
      for (int rr = 0; rr < 4; ++rr) {
        int m = rowoff + 4 * lg + rr;
        float sa = acc[rr] + bias + s_av[m * 66 + jt * 16 + lr];
        s_b1[m * 68 + jt * 16 + lr] = f2bf(fmaxf(sa, 0.f));
      }
    }
  }
  __syncthreads();
  // G4: X2 = relu(xnew) @ Wmid^T + bmid + temb2 -> global + s_av
  {
    Frag af = ldA(s_b1, rowoff + lr, lg);
    #pragma unroll
    for (int jtl = 0; jtl < 2; ++jtl) {
      int jt = jt0 + jtl;
      f32x4 acc = gemmW(af, Wt, jt * 16 + lr, lg);
      float bias = bt[jt * 16 + lr] + temb2[b * EE + jt * 16 + lr];
      #pragma unroll
      for (int rr = 0; rr < 4; ++rr) {
        int m = rowoff + 4 * lg + rr;
        float x2 = acc[rr] + bias;
        s_av[m * 66 + jt * 16 + lr] = x2;
        X2[(size_t)(m0 + m) * 64 + jt * 16 + lr] = x2;
      }
    }
  }
  __syncthreads();
  ln_stage(s_av, s_b1, g2, beta2, tid);
  __syncthreads();
  // G5: QKV projection for SA2
  {
    Frag af = ldA(s_b1, rowoff + lr, lg);
    const int jq0 = (w >> 1) * 6;
    const int q0s = (m0 & 1023) + rowoff + 4 * lg;
    #pragma unroll
    for (int jtl = 0; jtl < 6; ++jtl) {
      int jt = jq0 + jtl;
      f32x4 acc = gemmW(af, Wq, jt * 16 + lr, lg);
      float bias = bq[jt * 16 + lr];
      if (jt < 4) {
        ushort_t* dst = Qb + ((size_t)(b * NH + jt) * NN + q0s) * 16 + lr;
        #pragma unroll
        for (int rr = 0; rr < 4; ++rr) dst[rr * 16] = f2bf((acc[rr] + bias) * QSCALE);
      } else if (jt < 8) {
        ushort_t* dst = Kb + ((size_t)(b * NH + jt - 4) * NN + q0s) * 16 + lr;
        #pragma unroll
        for (int rr = 0; rr < 4; ++rr) dst[rr * 16] = f2bf(acc[rr] + bias);
      } else {
        ushort_t* dst = VT + ((size_t)(b * NH + jt - 8) * 16 + lr) * NN + q0s;
        bf16x4 pv = pack4(acc[0] + bias, acc[1] + bias, acc[2] + bias, acc[3] + bias);
        *reinterpret_cast<uint2*>(dst) = __builtin_bit_cast(uint2, pv);
      }
    }
  }
}

// ---------- SA2 tail: out-proj + res -> LN -> gelu-F1 -> F2+res -> final 3-col * mask ----------
__global__ __launch_bounds__(256) void ffn_final_kernel(
    const ushort_t* __restrict__ Ab, const float* __restrict__ Xres,
    const ushort_t* __restrict__ Wo, const float* __restrict__ bo,
    const float* __restrict__ g, const float* __restrict__ beta,
    const ushort_t* __restrict__ W1, const float* __restrict__ b1,
    const ushort_t* __restrict__ W2, const float* __restrict__ b2,
    const float* __restrict__ wout3, const float* __restrict__ bout3,
    const float* __restrict__ mask,
    float* __restrict__ Out)
{
  __shared__ ushort_t s_b1[32 * 68];
  __shared__ ushort_t s_b2[32 * 68];
  __shared__ float s_av[32 * 66];
  __shared__ float s_rs[32 * 66];
  const int tid = threadIdx.x;
  const int m0 = blockIdx.x * 32;
  const int r = tid >> 3, c0 = (tid & 7) * 8;
  {
    const uint2* ai = (const uint2*)(Ab + (size_t)(m0 + r) * 64 + c0);
    uint2* ao = (uint2*)&s_b1[r * 68 + c0];
    ao[0] = ai[0]; ao[1] = ai[1];
    const float4* xi = (const float4*)(Xres + (size_t)(m0 + r) * 64 + c0);
    float4* xo = (float4*)&s_rs[r * 66 + c0];
    xo[0] = xi[0]; xo[1] = xi[1];
  }
  __syncthreads();
  const int w = tid >> 6, l = tid & 63, lr = l & 15, lg = l >> 4;
  const int rowoff = (w & 1) * 16, jt0 = (w >> 1) * 2;
  {
    Frag af = ldA(s_b1, rowoff + lr, lg);
    #pragma unroll
    for (int jtl = 0; jtl < 2; ++jtl) {
      int jt = jt0 + jtl;
      f32x4 acc = gemmW(af, Wo, jt * 16 + lr, lg);
      float bias = bo[jt * 16 + lr];
      #pragma unroll
      for (int rr = 0; rr < 4; ++rr) {
        int m = rowoff + 4 * lg + rr;
        s_av[m * 66 + jt * 16 + lr] = acc[rr] + bias + s_rs[m * 66 + jt * 16 + lr];
      }
    }
  }
  __syncthreads();
  ln_stage(s_av, s_b1, g, beta, tid);
  __syncthreads();
  {
    Frag af = ldA(s_b1, rowoff + lr, lg);
    #pragma unroll
    for (int jtl = 0; jtl < 2; ++jtl) {
      int jt = jt0 + jtl;
      f32x4 acc = gemmW(af, W1, jt * 16 + lr, lg);
      float bias = b1[jt * 16 + lr];
      #pragma unroll
      for (int rr = 0; rr < 4; ++rr) {
        float t = acc[rr] + bias;
        t = 0.5f * t * (1.f + erff(t * 0.70710678118f));
        s_b2[(rowoff + 4 * lg + rr) * 68 + jt * 16 + lr] = f2bf(t);
      }
    }
  }
  __syncthreads();
  {
    Frag af = ldA(s_b2, rowoff + lr, lg);
    #pragma unroll
    for (int jtl = 0; jtl < 2; ++jtl) {
      int jt = jt0 + jtl;
      f32x4 acc = gemmW(af, W2, jt * 16 + lr, lg);
      float bias = b2[jt * 16 + lr];
      #pragma unroll
      for (int rr = 0; rr < 4; ++rr) {
        int m = rowoff + 4 * lg + rr;
        s_rs[m * 66 + jt * 16 + lr] = acc[rr] + bias + s_av[m * 66 + jt * 16 + lr];
      }
    }
  }
  __syncthreads();
  if (tid < 96) {
    int row = tid / 3, c = tid - row * 3;
    float acc = bout3[c];
    #pragma unroll 8
    for (int k = 0; k < 64; ++k)
      acc = fmaf(fmaxf(s_rs[row * 66 + k], 0.f), wout3[c * 64 + k], acc);
    Out[(size_t)(m0 + row) * 3 + c] = acc * mask[m0 + row];
  }
}

// ---------- host ----------
extern "C" void kernel_launch(void* const* d_in, const int* in_sizes, int n_in,
                              void* d_out, int out_size, void* d_ws, size_t ws_size,
                              hipStream_t stream)
{
  const float* pos    = (const float*)d_in[0];
  const float* t_int  = (const float*)d_in[1];
  const float* nmask  = (const float*)d_in[2];
  const float* w_in   = (const float*)d_in[3];
  const float* b_in   = (const float*)d_in[4];
  const float* w_mid  = (const float*)d_in[5];
  const float* b_mid  = (const float*)d_in[6];
  const float* w_out  = (const float*)d_in[7];
  const float* b_out  = (const float*)d_in[8];
  const float* e1w    = (const float*)d_in[9];
  const float* e1b    = (const float*)d_in[10];
  const float* e2w    = (const float*)d_in[11];
  const float* e2b    = (const float*)d_in[12];
  const float* const* SA1 = (const float* const*)(d_in + 13);
  const float* const* SA2 = (const float* const*)(d_in + 25);

  float* ws    = (float*)d_ws;
  float* temb1 = ws;
  float* temb2 = ws + 1024;
  float* X     = ws + 2048;
  float* X2    = X + (size_t)M_TOT * 64;
  ushort_t* ub = (ushort_t*)(X2 + (size_t)M_TOT * 64);
  ushort_t* Qb = ub;
  ushort_t* Kb = Qb + (size_t)BB * NH * NN * 16;
  ushort_t* VT = Kb + (size_t)BB * NH * NN * 16;
  ushort_t* Ab = VT + (size_t)BB * NH * NN * 16;
  ushort_t* Wb = Ab + (size_t)M_TOT * 64;
  ushort_t* Wqkv1 = Wb;
  ushort_t* Wo1   = Wb + 12288;
  ushort_t* W1_1  = Wb + 16384;
  ushort_t* W2_1  = Wb + 20480;
  ushort_t* Wqkv2 = Wb + 24576;
  ushort_t* Wo2   = Wb + 36864;
  ushort_t* W1_2  = Wb + 40960;
  ushort_t* W2_2  = Wb + 45056;
  ushort_t* Wmid  = Wb + 49152;

  prep_kernel<<<dim3(16, 10), 256, 0, stream>>>(
      SA1[2], SA1[4], SA1[8], SA1[10], SA2[2], SA2[4], SA2[8], SA2[10], w_mid, Wb,
      t_int, e1w, e1b, e2w, e2b, temb1, temb2);

  qkv1_kernel<<<M_TOT / 32, 256, 0, stream>>>(
      pos, w_in, b_in, temb1, X, SA1[0], SA1[1], Wqkv1, SA1[3], Qb, Kb, VT);
  attn_kernel<<<BB * NH * 32, 256, 0, stream>>>(Qb, Kb, VT, Ab);
  ffnq_kernel<<<M_TOT / 32, 256, 0, stream>>>(
      Ab, X, Wo1, SA1[5], SA1[6], SA1[7], W1_1, SA1[9], W2_1, SA1[11],
      Wmid, b_mid, temb2, SA2[0], SA2[1], Wqkv2, SA2[3], X2, Qb, Kb, VT);
  attn_kernel<<<BB * NH * 32, 256, 0, stream>>>(Qb, Kb, VT, Ab);
  ffn_final_kernel<<<M_TOT / 32, 256, 0, stream>>>(
      Ab, X2, Wo2, SA2[5], SA2[6], SA2[7], W1_2, SA2[9], W2_2, SA2[11],
      w_out, b_out, nmask, (float*)d_out);
}

// Round 8
// 83.964 us; speedup vs baseline: 16.5153x; 1.4984x over previous
//
#include <hip/hip_runtime.h>
#include <hip/hip_bf16.h>
#include <math.h>

// SimpleFC: B=16, N=1024, E=64, H=4, dh=16.
#define NH 4
#define EE 64
#define BB 16
#define NN 1024
#define M_TOT (BB * NN)
#define QSCALE 0.3606737602222409f   // 0.25 * log2(e)

typedef short bf16x4 __attribute__((ext_vector_type(4)));
typedef float f32x4 __attribute__((ext_vector_type(4)));
typedef unsigned short ushort_t;

// ---------- helpers (R4-proven) ----------
__device__ __forceinline__ unsigned int cvt_pk_bf16(float a, float b) {
  unsigned int r;
  asm("v_cvt_pk_bf16_f32 %0, %1, %2" : "=v"(r) : "v"(a), "v"(b));
  return r;
}
__device__ __forceinline__ ushort_t f2bf(float v) { return (ushort_t)cvt_pk_bf16(v, v); }
__device__ __forceinline__ bf16x4 pack4(float a, float b, float c, float d) {
  uint2 u; u.x = cvt_pk_bf16(a, b); u.y = cvt_pk_bf16(c, d);
  return __builtin_bit_cast(bf16x4, u);
}
__device__ __forceinline__ bf16x4 ldbf4(const ushort_t* p) {
  return __builtin_bit_cast(bf16x4, *reinterpret_cast<const uint2*>(p));
}

struct Frag { bf16x4 a[4]; };
__device__ __forceinline__ Frag ldA(const ushort_t* s, int row, int lg) {
  Frag f;
  #pragma unroll
  for (int kb = 0; kb < 4; ++kb) f.a[kb] = ldbf4(s + row * 68 + kb * 16 + 4 * lg);
  return f;
}
__device__ __forceinline__ f32x4 gemmW(const Frag& f, const ushort_t* W, int jcol, int lg) {
  f32x4 acc = {0.f, 0.f, 0.f, 0.f};
  const ushort_t* wb = W + jcol * 64 + 4 * lg;
  #pragma unroll
  for (int kb = 0; kb < 4; ++kb)
    acc = __builtin_amdgcn_mfma_f32_16x16x16bf16_1k(f.a[kb], ldbf4(wb + kb * 16), acc, 0, 0, 0);
  return acc;
}
// LN a 32x64 f32 LDS tile (stride 66) -> bf16 LDS tile (stride 68). 8 threads/row. (R4-proven)
__device__ __forceinline__ void ln_stage(const float* s_src, ushort_t* s_dst,
    const float* __restrict__ g, const float* __restrict__ beta, int tid) {
  int r = tid >> 3, c0 = (tid & 7) * 8;
  float v[8];
  #pragma unroll
  for (int j = 0; j < 8; ++j) v[j] = s_src[r * 66 + c0 + j];
  float s = 0.f;
  #pragma unroll
  for (int j = 0; j < 8; ++j) s += v[j];
  s += __shfl_xor(s, 1); s += __shfl_xor(s, 2); s += __shfl_xor(s, 4);
  float mean = s * (1.f / EE);
  float qv = 0.f;
  #pragma unroll
  for (int j = 0; j < 8; ++j) { float d = v[j] - mean; qv += d * d; }
  qv += __shfl_xor(qv, 1); qv += __shfl_xor(qv, 2); qv += __shfl_xor(qv, 4);
  float rs = rsqrtf(qv * (1.f / EE) + 1e-5f);
  unsigned int* dst = (unsigned int*)(s_dst + r * 68 + c0);
  #pragma unroll
  for (int j = 0; j < 4; ++j) {
    float h0 = (v[2*j]   - mean) * rs * g[c0 + 2*j]   + beta[c0 + 2*j];
    float h1 = (v[2*j+1] - mean) * rs * g[c0 + 2*j+1] + beta[c0 + 2*j+1];
    dst[j] = cvt_pk_bf16(h0, h1);
  }
}

// ---------- prep: weight f32->bf16 (y<9) + timestep embedding (y==9) ----------
__global__ __launch_bounds__(256) void prep_kernel(
    const float* a0, const float* a1, const float* a2, const float* a3,
    const float* a4, const float* a5, const float* a6, const float* a7,
    const float* a8, ushort_t* __restrict__ dst,
    const float* __restrict__ t_int,
    const float* __restrict__ e1w, const float* __restrict__ e1b,
    const float* __restrict__ e2w, const float* __restrict__ e2b,
    float* __restrict__ temb1, float* __restrict__ temb2)
{
  if (blockIdx.y < 9) {
    const int off[9] = {0, 12288, 16384, 20480, 24576, 36864, 40960, 45056, 49152};
    const int sz[9]  = {12288, 4096, 4096, 4096, 12288, 4096, 4096, 4096, 4096};
    const float* srcs[9] = {a0, a1, a2, a3, a4, a5, a6, a7, a8};
    int s = blockIdx.y;
    const float* src = srcs[s];
    for (int i = blockIdx.x * 256 + threadIdx.x; i < sz[s]; i += 16 * 256)
      dst[off[s] + i] = f2bf(src[i]);
    return;
  }
  __shared__ float s_silu[EE];
  int b = blockIdx.x, e = threadIdx.x;
  if (e >= 64) return;
  float t = t_int[b];
  int i = e & 31;
  float inv_freq = powf(10000.f, -(float)(2 * i) / (float)EE);
  float ang = t * inv_freq;
  float ti = (e < 32) ? sinf(ang) : cosf(ang);
  s_silu[e] = ti / (1.f + expf(-ti));
  __syncthreads();
  float v1 = e1b[e], v2 = e2b[e];
  #pragma unroll 8
  for (int k = 0; k < EE; ++k) {
    float s = s_silu[k];
    v1 = fmaf(s, e1w[e * EE + k], v1);
    v2 = fmaf(s, e2w[e * EE + k], v2);
  }
  temb1[b * EE + e] = v1;
  temb2[b * EE + e] = v2;
}

// ---------- xinit + LN + QKV projection (SA1 entry). 32-row tile, col-split waves ----------
__global__ __launch_bounds__(256) void qkv1_kernel(
    const float* __restrict__ pos,
    const float* __restrict__ w_in, const float* __restrict__ b_in,
    const float* __restrict__ temb1, float* __restrict__ Xout,
    const float* __restrict__ g, const float* __restrict__ beta,
    const ushort_t* __restrict__ Wq, const float* __restrict__ bq,
    ushort_t* __restrict__ Qb, ushort_t* __restrict__ Kb, ushort_t* __restrict__ VT)
{
  __shared__ ushort_t s_h[32 * 68];
  const int tid = threadIdx.x;
  const int m0 = blockIdx.x * 32;
  const int b = m0 >> 10;
  const int r = tid >> 3, c0 = (tid & 7) * 8;
  float v[8];
  {
    const float* pr = pos + (size_t)(m0 + r) * 3;
    float p0 = pr[0], p1 = pr[1], p2 = pr[2];
    #pragma unroll
    for (int j = 0; j < 8; ++j) {
      int c = c0 + j;
      float t = b_in[c] + temb1[b * EE + c];
      t = fmaf(p0, w_in[c * 3 + 0], t);
      t = fmaf(p1, w_in[c * 3 + 1], t);
      t = fmaf(p2, w_in[c * 3 + 2], t);
      v[j] = t;
    }
    float4* xo = (float4*)(Xout + (size_t)(m0 + r) * 64 + c0);
    float4 t4a = {v[0], v[1], v[2], v[3]}, t4b = {v[4], v[5], v[6], v[7]};
    xo[0] = t4a; xo[1] = t4b;
  }
  float s = 0.f;
  #pragma unroll
  for (int j = 0; j < 8; ++j) s += v[j];
  s += __shfl_xor(s, 1); s += __shfl_xor(s, 2); s += __shfl_xor(s, 4);
  float mean = s * (1.f / EE);
  float qv = 0.f;
  #pragma unroll
  for (int j = 0; j < 8; ++j) { float d = v[j] - mean; qv += d * d; }
  qv += __shfl_xor(qv, 1); qv += __shfl_xor(qv, 2); qv += __shfl_xor(qv, 4);
  float rs = rsqrtf(qv * (1.f / EE) + 1e-5f);
  {
    unsigned int* sh = (unsigned int*)&s_h[r * 68 + c0];
    #pragma unroll
    for (int j = 0; j < 4; ++j) {
      float h0 = (v[2*j]   - mean) * rs * g[c0 + 2*j]   + beta[c0 + 2*j];
      float h1 = (v[2*j+1] - mean) * rs * g[c0 + 2*j+1] + beta[c0 + 2*j+1];
      sh[j] = cvt_pk_bf16(h0, h1);
    }
  }
  __syncthreads();
  const int w = tid >> 6, l = tid & 63, lr = l & 15, lg = l >> 4;
  const int rowoff = (w & 1) * 16, jt0 = (w >> 1) * 6;
  Frag af = ldA(s_h, rowoff + lr, lg);
  const int q0s = (m0 & 1023) + rowoff + 4 * lg;
  #pragma unroll
  for (int jtl = 0; jtl < 6; ++jtl) {
    int jt = jt0 + jtl;
    f32x4 acc = gemmW(af, Wq, jt * 16 + lr, lg);
    float bias = bq[jt * 16 + lr];
    if (jt < 4) {
      ushort_t* dst = Qb + ((size_t)(b * NH + jt) * NN + q0s) * 16 + lr;
      #pragma unroll
      for (int rr = 0; rr < 4; ++rr) dst[rr * 16] = f2bf((acc[rr] + bias) * QSCALE);
    } else if (jt < 8) {
      ushort_t* dst = Kb + ((size_t)(b * NH + jt - 4) * NN + q0s) * 16 + lr;
      #pragma unroll
      for (int rr = 0; rr < 4; ++rr) dst[rr * 16] = f2bf(acc[rr] + bias);
    } else {
      ushort_t* dst = VT + ((size_t)(b * NH + jt - 8) * 16 + lr) * NN + q0s;
      bf16x4 pv = pack4(acc[0] + bias, acc[1] + bias, acc[2] + bias, acc[3] + bias);
      *reinterpret_cast<uint2*>(dst) = __builtin_bit_cast(uint2, pv);
    }
  }
}

// ---------- MFMA flash attention v2: V^T staged in LDS, K from L2 with prefetch ----------
// grid = 64 bh * 16 qgroup = 1024 blocks; block = 4 waves, each wave = 16 queries, full 1024 kv.
// V^T LDS stride 1034 shorts (517 banks == 5 mod 32, odd -> conflict-free b32-pair reads;
// 8B-aligned rows + odd bank stride are mutually exclusive, hence b32 pairs not b64).
__global__ __launch_bounds__(256) void attn_kernel(
    const ushort_t* __restrict__ Qb, const ushort_t* __restrict__ Kb,
    const ushort_t* __restrict__ VT, ushort_t* __restrict__ Ab)
{
  __shared__ ushort_t s_v[16 * 1034];   // 33 KB
  const int tid = threadIdx.x, w = tid >> 6, l = tid & 63, lr = l & 15, lg = l >> 4;
  const int bid = blockIdx.x;
  const int blk = ((bid & 7) << 7) | (bid >> 3);   // XCD-aware bijection (1024 = 8*128)
  const int bh = blk >> 4, qg = blk & 15;
  const int q0 = qg * 64 + w * 16;
  // ---- stage V^T[16][1024] -> s_v[16][1034] (coalesced 16B loads, b32 LDS writes)
  {
    const ushort_t* vsrc = VT + (size_t)bh * 16 * NN;
    #pragma unroll
    for (int i = 0; i < 8; ++i) {
      int idx = i * 2048 + tid * 8;
      int row = idx >> 10, col = idx & 1023;
      uint4 d = *reinterpret_cast<const uint4*>(vsrc + row * NN + col);
      unsigned int* ds = (unsigned int*)&s_v[row * 1034 + col];
      ds[0] = d.x; ds[1] = d.y; ds[2] = d.z; ds[3] = d.w;
    }
  }
  __syncthreads();
  // ---- main sweep
  bf16x4 qf = ldbf4(Qb + ((size_t)bh * NN + q0 + lr) * 16 + 4 * lg);
  const ushort_t* kp = Kb + (size_t)bh * NN * 16 + lr * 16 + 4 * lg;
  const int vbase = lr * 1034 + 4 * lg;
  f32x4 oA = {0.f, 0.f, 0.f, 0.f}, oB = {0.f, 0.f, 0.f, 0.f};
  float psA = 0.f, psB = 0.f;
  bf16x4 kf = ldbf4(kp);   // distance-1 prefetch
  #pragma unroll 4
  for (int c = 0; c < 64; ++c) {
    bf16x4 kf_n;
    if (c < 63) kf_n = ldbf4(kp + (c + 1) * 256);
    unsigned int v0 = *(const unsigned int*)&s_v[vbase + c * 16];
    unsigned int v1 = *(const unsigned int*)&s_v[vbase + c * 16 + 2];
    uint2 vu; vu.x = v0; vu.y = v1;
    bf16x4 vf = __builtin_bit_cast(bf16x4, vu);
    f32x4 z = {0.f, 0.f, 0.f, 0.f};
    f32x4 st = __builtin_amdgcn_mfma_f32_16x16x16bf16_1k(kf, qf, z, 0, 0, 0);
    float p0 = __builtin_amdgcn_exp2f(st[0]);
    float p1 = __builtin_amdgcn_exp2f(st[1]);
    float p2 = __builtin_amdgcn_exp2f(st[2]);
    float p3 = __builtin_amdgcn_exp2f(st[3]);
    bf16x4 pf = pack4(p0, p1, p2, p3);
    if (c & 1) {
      psB += (p0 + p1) + (p2 + p3);
      oB = __builtin_amdgcn_mfma_f32_16x16x16bf16_1k(vf, pf, oB, 0, 0, 0);
    } else {
      psA += (p0 + p1) + (p2 + p3);
      oA = __builtin_amdgcn_mfma_f32_16x16x16bf16_1k(vf, pf, oA, 0, 0, 0);
    }
    kf = kf_n;
  }
  float ps = psA + psB;
  ps += __shfl_xor(ps, 16);
  ps += __shfl_xor(ps, 32);
  float inv = 1.f / ps;
  const int b = bh >> 2, h = bh & 3;
  ushort_t* dst = Ab + ((size_t)b * NN + q0 + lr) * 64 + h * 16 + 4 * lg;
  bf16x4 ov = pack4((oA[0] + oB[0]) * inv, (oA[1] + oB[1]) * inv,
                    (oA[2] + oB[2]) * inv, (oA[3] + oB[3]) * inv);
  *reinterpret_cast<uint2*>(dst) = __builtin_bit_cast(uint2, ov);
}

// ---------- SA1 tail: out-proj + res -> LN -> gelu-F1 -> F2+res -> mid-linear -> LN -> QKV(SA2) ----------
__global__ __launch_bounds__(256) void ffnq_kernel(
    const ushort_t* __restrict__ Ab, const float* __restrict__ Xres,
    const ushort_t* __restrict__ Wo, const float* __restrict__ bo,
    const float* __restrict__ g, const float* __restrict__ beta,
    const ushort_t* __restrict__ W1, const float* __restrict__ b1,
    const ushort_t* __restrict__ W2, const float* __restrict__ b2,
    const ushort_t* __restrict__ Wt, const float* __restrict__ bt,
    const float* __restrict__ temb2,
    const float* __restrict__ g2, const float* __restrict__ beta2,
    const ushort_t* __restrict__ Wq, const float* __restrict__ bq,
    float* __restrict__ X2,
    ushort_t* __restrict__ Qb, ushort_t* __restrict__ Kb, ushort_t* __restrict__ VT)
{
  __shared__ ushort_t s_b1[32 * 68];
  __shared__ ushort_t s_b2[32 * 68];
  __shared__ float s_av[32 * 66];
  __shared__ float s_rs[32 * 66];
  const int tid = threadIdx.x;
  const int m0 = blockIdx.x * 32, b = m0 >> 10;
  const int r = tid >> 3, c0 = (tid & 7) * 8;
  {
    const uint2* ai = (const uint2*)(Ab + (size_t)(m0 + r) * 64 + c0);
    uint2* ao = (uint2*)&s_b1[r * 68 + c0];
    ao[0] = ai[0]; ao[1] = ai[1];
    const float4* xi = (const float4*)(Xres + (size_t)(m0 + r) * 64 + c0);
    float4* xo = (float4*)&s_rs[r * 66 + c0];
    xo[0] = xi[0]; xo[1] = xi[1];
  }
  __syncthreads();
  const int w = tid >> 6, l = tid & 63, lr = l & 15, lg = l >> 4;
  const int rowoff = (w & 1) * 16, jt0 = (w >> 1) * 2;
  // G1: av = A @ Wo^T + bo + Xres -> s_av
  {
    Frag af = ldA(s_b1, rowoff + lr, lg);
    #pragma unroll
    for (int jtl = 0; jtl < 2; ++jtl) {
      int jt = jt0 + jtl;
      f32x4 acc = gemmW(af, Wo, jt * 16 + lr, lg);
      float bias = bo[jt * 16 + lr];
      #pragma unroll
      for (int rr = 0; rr < 4; ++rr) {
        int m = rowoff + 4 * lg + rr;
        s_av[m * 66 + jt * 16 + lr] = acc[rr] + bias + s_rs[m * 66 + jt * 16 + lr];
      }
    }
  }
  __syncthreads();
  ln_stage(s_av, s_b1, g, beta, tid);
  __syncthreads();
  // G2: gelu(h @ W1^T + b1) -> s_b2
  {
    Frag af = ldA(s_b1, rowoff + lr, lg);
    #pragma unroll
    for (int jtl = 0; jtl < 2; ++jtl) {
      int jt = jt0 + jtl;
      f32x4 acc = gemmW(af, W1, jt * 16 + lr, lg);
      float bias = b1[jt * 16 + lr];
      #pragma unroll
      for (int rr = 0; rr < 4; ++rr) {
        float t = acc[rr] + bias;
        t = 0.5f * t * (1.f + erff(t * 0.70710678118f));
        s_b2[(rowoff + 4 * lg + rr) * 68 + jt * 16 + lr] = f2bf(t);
      }
    }
  }
  __syncthreads();
  // G3: xnew = h1 @ W2^T + b2 + av; store relu(xnew) bf16 -> s_b1
  {
    Frag af = ldA(s_b2, rowoff + lr, lg);
    #pragma unroll
    for (int jtl = 0; jtl < 2; ++jtl) {
      int jt = jt0 + jtl;
      f32x4 acc = gemmW(af, W2, jt * 16 + lr, lg);
      float bias = b2[jt * 16 + lr];
      #pragma unroll
      for (int rr = 0; rr < 4; ++rr) {
        int m = rowoff + 4 * lg + rr;
        float sa = acc[rr] + bias + s_av[m * 66 + jt * 16 + lr];
        s_b1[m * 68 + jt * 16 + lr] = f2bf(fmaxf(sa, 0.f));
      }
    }
  }
  __syncthreads();
  // G4: X2 = relu(xnew) @ Wmid^T + bmid + temb2 -> global + s_av
  {
    Frag af = ldA(s_b1, rowoff + lr, lg);
    #pragma unroll
    for (int jtl = 0; jtl < 2; ++jtl) {
      int jt = jt0 + jtl;
      f32x4 acc = gemmW(af, Wt, jt * 16 + lr, lg);
      float bias = bt[jt * 16 + lr] + temb2[b * EE + jt * 16 + lr];
      #pragma unroll
      for (int rr = 0; rr < 4; ++rr) {
        int m = rowoff + 4 * lg + rr;
        float x2 = acc[rr] + bias;
        s_av[m * 66 + jt * 16 + lr] = x2;
        X2[(size_t)(m0 + m) * 64 + jt * 16 + lr] = x2;
      }
    }
  }
  __syncthreads();
  ln_stage(s_av, s_b1, g2, beta2, tid);
  __syncthreads();
  // G5: QKV projection for SA2
  {
    Frag af = ldA(s_b1, rowoff + lr, lg);
    const int jq0 = (w >> 1) * 6;
    const int q0s = (m0 & 1023) + rowoff + 4 * lg;
    #pragma unroll
    for (int jtl = 0; jtl < 6; ++jtl) {
      int jt = jq0 + jtl;
      f32x4 acc = gemmW(af, Wq, jt * 16 + lr, lg);
      float bias = bq[jt * 16 + lr];
      if (jt < 4) {
        ushort_t* dst = Qb + ((size_t)(b * NH + jt) * NN + q0s) * 16 + lr;
        #pragma unroll
        for (int rr = 0; rr < 4; ++rr) dst[rr * 16] = f2bf((acc[rr] + bias) * QSCALE);
      } else if (jt < 8) {
        ushort_t* dst = Kb + ((size_t)(b * NH + jt - 4) * NN + q0s) * 16 + lr;
        #pragma unroll
        for (int rr = 0; rr < 4; ++rr) dst[rr * 16] = f2bf(acc[rr] + bias);
      } else {
        ushort_t* dst = VT + ((size_t)(b * NH + jt - 8) * 16 + lr) * NN + q0s;
        bf16x4 pv = pack4(acc[0] + bias, acc[1] + bias, acc[2] + bias, acc[3] + bias);
        *reinterpret_cast<uint2*>(dst) = __builtin_bit_cast(uint2, pv);
      }
    }
  }
}

// ---------- SA2 tail: out-proj + res -> LN -> gelu-F1 -> F2+res -> final 3-col * mask ----------
__global__ __launch_bounds__(256) void ffn_final_kernel(
    const ushort_t* __restrict__ Ab, const float* __restrict__ Xres,
    const ushort_t* __restrict__ Wo, const float* __restrict__ bo,
    const float* __restrict__ g, const float* __restrict__ beta,
    const ushort_t* __restrict__ W1, const float* __restrict__ b1,
    const ushort_t* __restrict__ W2, const float* __restrict__ b2,
    const float* __restrict__ wout3, const float* __restrict__ bout3,
    const float* __restrict__ mask,
    float* __restrict__ Out)
{
  __shared__ ushort_t s_b1[32 * 68];
  __shared__ ushort_t s_b2[32 * 68];
  __shared__ float s_av[32 * 66];
  __shared__ float s_rs[32 * 66];
  const int tid = threadIdx.x;
  const int m0 = blockIdx.x * 32;
  const int r = tid >> 3, c0 = (tid & 7) * 8;
  {
    const uint2* ai = (const uint2*)(Ab + (size_t)(m0 + r) * 64 + c0);
    uint2* ao = (uint2*)&s_b1[r * 68 + c0];
    ao[0] = ai[0]; ao[1] = ai[1];
    const float4* xi = (const float4*)(Xres + (size_t)(m0 + r) * 64 + c0);
    float4* xo = (float4*)&s_rs[r * 66 + c0];
    xo[0] = xi[0]; xo[1] = xi[1];
  }
  __syncthreads();
  const int w = tid >> 6, l = tid & 63, lr = l & 15, lg = l >> 4;
  const int rowoff = (w & 1) * 16, jt0 = (w >> 1) * 2;
  {
    Frag af = ldA(s_b1, rowoff + lr, lg);
    #pragma unroll
    for (int jtl = 0; jtl < 2; ++jtl) {
      int jt = jt0 + jtl;
      f32x4 acc = gemmW(af, Wo, jt * 16 + lr, lg);
      float bias = bo[jt * 16 + lr];
      #pragma unroll
      for (int rr = 0; rr < 4; ++rr) {
        int m = rowoff + 4 * lg + rr;
        s_av[m * 66 + jt * 16 + lr] = acc[rr] + bias + s_rs[m * 66 + jt * 16 + lr];
      }
    }
  }
  __syncthreads();
  ln_stage(s_av, s_b1, g, beta, tid);
  __syncthreads();
  {
    Frag af = ldA(s_b1, rowoff + lr, lg);
    #pragma unroll
    for (int jtl = 0; jtl < 2; ++jtl) {
      int jt = jt0 + jtl;
      f32x4 acc = gemmW(af, W1, jt * 16 + lr, lg);
      float bias = b1[jt * 16 + lr];
      #pragma unroll
      for (int rr = 0; rr < 4; ++rr) {
        float t = acc[rr] + bias;
        t = 0.5f * t * (1.f + erff(t * 0.70710678118f));
        s_b2[(rowoff + 4 * lg + rr) * 68 + jt * 16 + lr] = f2bf(t);
      }
    }
  }
  __syncthreads();
  {
    Frag af = ldA(s_b2, rowoff + lr, lg);
    #pragma unroll
    for (int jtl = 0; jtl < 2; ++jtl) {
      int jt = jt0 + jtl;
      f32x4 acc = gemmW(af, W2, jt * 16 + lr, lg);
      float bias = b2[jt * 16 + lr];
      #pragma unroll
      for (int rr = 0; rr < 4; ++rr) {
        int m = rowoff + 4 * lg + rr;
        s_rs[m * 66 + jt * 16 + lr] = acc[rr] + bias + s_av[m * 66 + jt * 16 + lr];
      }
    }
  }
  __syncthreads();
  if (tid < 96) {
    int row = tid / 3, c = tid - row * 3;
    float acc = bout3[c];
    #pragma unroll 8
    for (int k = 0; k < 64; ++k)
      acc = fmaf(fmaxf(s_rs[row * 66 + k], 0.f), wout3[c * 64 + k], acc);
    Out[(size_t)(m0 + row) * 3 + c] = acc * mask[m0 + row];
  }
}

// ---------- host ----------
extern "C" void kernel_launch(void* const* d_in, const int* in_sizes, int n_in,
                              void* d_out, int out_size, void* d_ws, size_t ws_size,
                              hipStream_t stream)
{
  const float* pos    = (const float*)d_in[0];
  const float* t_int  = (const float*)d_in[1];
  const float* nmask  = (const float*)d_in[2];
  const float* w_in   = (const float*)d_in[3];
  const float* b_in   = (const float*)d_in[4];
  const float* w_mid  = (const float*)d_in[5];
  const float* b_mid  = (const float*)d_in[6];
  const float* w_out  = (const float*)d_in[7];
  const float* b_out  = (const float*)d_in[8];
  const float* e1w    = (const float*)d_in[9];
  const float* e1b    = (const float*)d_in[10];
  const float* e2w    = (const float*)d_in[11];
  const float* e2b    = (const float*)d_in[12];
  const float* const* SA1 = (const float* const*)(d_in + 13);
  const float* const* SA2 = (const float* const*)(d_in + 25);

  float* ws    = (float*)d_ws;
  float* temb1 = ws;
  float* temb2 = ws + 1024;
  float* X     = ws + 2048;
  float* X2    = X + (size_t)M_TOT * 64;
  ushort_t* ub = (ushort_t*)(X2 + (size_t)M_TOT * 64);
  ushort_t* Qb = ub;
  ushort_t* Kb = Qb + (size_t)BB * NH * NN * 16;
  ushort_t* VT = Kb + (size_t)BB * NH * NN * 16;
  ushort_t* Ab = VT + (size_t)BB * NH * NN * 16;
  ushort_t* Wb = Ab + (size_t)M_TOT * 64;
  ushort_t* Wqkv1 = Wb;
  ushort_t* Wo1   = Wb + 12288;
  ushort_t* W1_1  = Wb + 16384;
  ushort_t* W2_1  = Wb + 20480;
  ushort_t* Wqkv2 = Wb + 24576;
  ushort_t* Wo2   = Wb + 36864;
  ushort_t* W1_2  = Wb + 40960;
  ushort_t* W2_2  = Wb + 45056;
  ushort_t* Wmid  = Wb + 49152;

  prep_kernel<<<dim3(16, 10), 256, 0, stream>>>(
      SA1[2], SA1[4], SA1[8], SA1[10], SA2[2], SA2[4], SA2[8], SA2[10], w_mid, Wb,
      t_int, e1w, e1b, e2w, e2b, temb1, temb2);

  qkv1_kernel<<<M_TOT / 32, 256, 0, stream>>>(
      pos, w_in, b_in, temb1, X, SA1[0], SA1[1], Wqkv1, SA1[3], Qb, Kb, VT);
  attn_kernel<<<BB * NH * 16, 256, 0, stream>>>(Qb, Kb, VT, Ab);
  ffnq_kernel<<<M_TOT / 32, 256, 0, stream>>>(
      Ab, X, Wo1, SA1[5], SA1[6], SA1[7], W1_1, SA1[9], W2_1, SA1[11],
      Wmid, b_mid, temb2, SA2[0], SA2[1], Wqkv2, SA2[3], X2, Qb, Kb, VT);
  attn_kernel<<<BB * NH * 16, 256, 0, stream>>>(Qb, Kb, VT, Ab);
  ffn_final_kernel<<<M_TOT / 32, 256, 0, stream>>>(
      Ab, X2, Wo2, SA2[5], SA2[6], SA2[7], W1_2, SA2[9], W2_2, SA2[11],
      w_out, b_out, nmask, (float*)d_out);
}

// Round 9
// 79.834 us; speedup vs baseline: 17.3697x; 1.0517x over previous
//
#include <hip/hip_runtime.h>
#include <hip/hip_bf16.h>
#include <math.h>

// SimpleFC: B=16, N=1024, E=64, H=4, dh=16.
#define NH 4
#define EE 64
#define BB 16
#define NN 1024
#define M_TOT (BB * NN)
#define QSCALE 0.3606737602222409f   // 0.25 * log2(e)

typedef short bf16x4 __attribute__((ext_vector_type(4)));
typedef float f32x4 __attribute__((ext_vector_type(4)));
typedef unsigned short ushort_t;

// ---------- helpers (R4-proven) ----------
__device__ __forceinline__ unsigned int cvt_pk_bf16(float a, float b) {
  unsigned int r;
  asm("v_cvt_pk_bf16_f32 %0, %1, %2" : "=v"(r) : "v"(a), "v"(b));
  return r;
}
__device__ __forceinline__ ushort_t f2bf(float v) { return (ushort_t)cvt_pk_bf16(v, v); }
__device__ __forceinline__ bf16x4 pack4(float a, float b, float c, float d) {
  uint2 u; u.x = cvt_pk_bf16(a, b); u.y = cvt_pk_bf16(c, d);
  return __builtin_bit_cast(bf16x4, u);
}
__device__ __forceinline__ bf16x4 ldbf4(const ushort_t* p) {
  return __builtin_bit_cast(bf16x4, *reinterpret_cast<const uint2*>(p));
}

struct Frag { bf16x4 a[4]; };
__device__ __forceinline__ Frag ldA(const ushort_t* s, int row, int lg) {
  Frag f;
  #pragma unroll
  for (int kb = 0; kb < 4; ++kb) f.a[kb] = ldbf4(s + row * 68 + kb * 16 + 4 * lg);
  return f;
}
__device__ __forceinline__ f32x4 gemmW(const Frag& f, const ushort_t* W, int jcol, int lg) {
  f32x4 acc = {0.f, 0.f, 0.f, 0.f};
  const ushort_t* wb = W + jcol * 64 + 4 * lg;
  #pragma unroll
  for (int kb = 0; kb < 4; ++kb)
    acc = __builtin_amdgcn_mfma_f32_16x16x16bf16_1k(f.a[kb], ldbf4(wb + kb * 16), acc, 0, 0, 0);
  return acc;
}
// LN a 32x64 f32 LDS tile (stride 66) -> bf16 LDS tile (stride 68). 8 threads/row. (R4-proven)
__device__ __forceinline__ void ln_stage(const float* s_src, ushort_t* s_dst,
    const float* __restrict__ g, const float* __restrict__ beta, int tid) {
  int r = tid >> 3, c0 = (tid & 7) * 8;
  float v[8];
  #pragma unroll
  for (int j = 0; j < 8; ++j) v[j] = s_src[r * 66 + c0 + j];
  float s = 0.f;
  #pragma unroll
  for (int j = 0; j < 8; ++j) s += v[j];
  s += __shfl_xor(s, 1); s += __shfl_xor(s, 2); s += __shfl_xor(s, 4);
  float mean = s * (1.f / EE);
  float qv = 0.f;
  #pragma unroll
  for (int j = 0; j < 8; ++j) { float d = v[j] - mean; qv += d * d; }
  qv += __shfl_xor(qv, 1); qv += __shfl_xor(qv, 2); qv += __shfl_xor(qv, 4);
  float rs = rsqrtf(qv * (1.f / EE) + 1e-5f);
  unsigned int* dst = (unsigned int*)(s_dst + r * 68 + c0);
  #pragma unroll
  for (int j = 0; j < 4; ++j) {
    float h0 = (v[2*j]   - mean) * rs * g[c0 + 2*j]   + beta[c0 + 2*j];
    float h1 = (v[2*j+1] - mean) * rs * g[c0 + 2*j+1] + beta[c0 + 2*j+1];
    dst[j] = cvt_pk_bf16(h0, h1);
  }
}

// ---------- prep: weight f32->bf16 (y<9) + timestep embedding (y==9) ----------
__global__ __launch_bounds__(256) void prep_kernel(
    const float* a0, const float* a1, const float* a2, const float* a3,
    const float* a4, const float* a5, const float* a6, const float* a7,
    const float* a8, ushort_t* __restrict__ dst,
    const float* __restrict__ t_int,
    const float* __restrict__ e1w, const float* __restrict__ e1b,
    const float* __restrict__ e2w, const float* __restrict__ e2b,
    float* __restrict__ temb1, float* __restrict__ temb2)
{
  if (blockIdx.y < 9) {
    const int off[9] = {0, 12288, 16384, 20480, 24576, 36864, 40960, 45056, 49152};
    const int sz[9]  = {12288, 4096, 4096, 4096, 12288, 4096, 4096, 4096, 4096};
    const float* srcs[9] = {a0, a1, a2, a3, a4, a5, a6, a7, a8};
    int s = blockIdx.y;
    const float* src = srcs[s];
    for (int i = blockIdx.x * 256 + threadIdx.x; i < sz[s]; i += 16 * 256)
      dst[off[s] + i] = f2bf(src[i]);
    return;
  }
  __shared__ float s_silu[EE];
  int b = blockIdx.x, e = threadIdx.x;
  if (e >= 64) return;
  float t = t_int[b];
  int i = e & 31;
  float inv_freq = powf(10000.f, -(float)(2 * i) / (float)EE);
  float ang = t * inv_freq;
  float ti = (e < 32) ? sinf(ang) : cosf(ang);
  s_silu[e] = ti / (1.f + expf(-ti));
  __syncthreads();
  float v1 = e1b[e], v2 = e2b[e];
  #pragma unroll 8
  for (int k = 0; k < EE; ++k) {
    float s = s_silu[k];
    v1 = fmaf(s, e1w[e * EE + k], v1);
    v2 = fmaf(s, e2w[e * EE + k], v2);
  }
  temb1[b * EE + e] = v1;
  temb2[b * EE + e] = v2;
}

// ---------- xinit + LN + QKV projection (SA1 entry). 32-row tile, col-split waves ----------
__global__ __launch_bounds__(256) void qkv1_kernel(
    const float* __restrict__ pos,
    const float* __restrict__ w_in, const float* __restrict__ b_in,
    const float* __restrict__ temb1, float* __restrict__ Xout,
    const float* __restrict__ g, const float* __restrict__ beta,
    const ushort_t* __restrict__ Wq, const float* __restrict__ bq,
    ushort_t* __restrict__ Qb, ushort_t* __restrict__ Kb, ushort_t* __restrict__ VT)
{
  __shared__ ushort_t s_h[32 * 68];
  const int tid = threadIdx.x;
  const int m0 = blockIdx.x * 32;
  const int b = m0 >> 10;
  const int r = tid >> 3, c0 = (tid & 7) * 8;
  float v[8];
  {
    const float* pr = pos + (size_t)(m0 + r) * 3;
    float p0 = pr[0], p1 = pr[1], p2 = pr[2];
    #pragma unroll
    for (int j = 0; j < 8; ++j) {
      int c = c0 + j;
      float t = b_in[c] + temb1[b * EE + c];
      t = fmaf(p0, w_in[c * 3 + 0], t);
      t = fmaf(p1, w_in[c * 3 + 1], t);
      t = fmaf(p2, w_in[c * 3 + 2], t);
      v[j] = t;
    }
    float4* xo = (float4*)(Xout + (size_t)(m0 + r) * 64 + c0);
    float4 t4a = {v[0], v[1], v[2], v[3]}, t4b = {v[4], v[5], v[6], v[7]};
    xo[0] = t4a; xo[1] = t4b;
  }
  float s = 0.f;
  #pragma unroll
  for (int j = 0; j < 8; ++j) s += v[j];
  s += __shfl_xor(s, 1); s += __shfl_xor(s, 2); s += __shfl_xor(s, 4);
  float mean = s * (1.f / EE);
  float qv = 0.f;
  #pragma unroll
  for (int j = 0; j < 8; ++j) { float d = v[j] - mean; qv += d * d; }
  qv += __shfl_xor(qv, 1); qv += __shfl_xor(qv, 2); qv += __shfl_xor(qv, 4);
  float rs = rsqrtf(qv * (1.f / EE) + 1e-5f);
  {
    unsigned int* sh = (unsigned int*)&s_h[r * 68 + c0];
    #pragma unroll
    for (int j = 0; j < 4; ++j) {
      float h0 = (v[2*j]   - mean) * rs * g[c0 + 2*j]   + beta[c0 + 2*j];
      float h1 = (v[2*j+1] - mean) * rs * g[c0 + 2*j+1] + beta[c0 + 2*j+1];
      sh[j] = cvt_pk_bf16(h0, h1);
    }
  }
  __syncthreads();
  const int w = tid >> 6, l = tid & 63, lr = l & 15, lg = l >> 4;
  const int rowoff = (w & 1) * 16, jt0 = (w >> 1) * 6;
  Frag af = ldA(s_h, rowoff + lr, lg);
  const int q0s = (m0 & 1023) + rowoff + 4 * lg;
  #pragma unroll
  for (int jtl = 0; jtl < 6; ++jtl) {
    int jt = jt0 + jtl;
    f32x4 acc = gemmW(af, Wq, jt * 16 + lr, lg);
    float bias = bq[jt * 16 + lr];
    if (jt < 4) {
      ushort_t* dst = Qb + ((size_t)(b * NH + jt) * NN + q0s) * 16 + lr;
      #pragma unroll
      for (int rr = 0; rr < 4; ++rr) dst[rr * 16] = f2bf((acc[rr] + bias) * QSCALE);
    } else if (jt < 8) {
      ushort_t* dst = Kb + ((size_t)(b * NH + jt - 4) * NN + q0s) * 16 + lr;
      #pragma unroll
      for (int rr = 0; rr < 4; ++rr) dst[rr * 16] = f2bf(acc[rr] + bias);
    } else {
      ushort_t* dst = VT + ((size_t)(b * NH + jt - 8) * 16 + lr) * NN + q0s;
      bf16x4 pv = pack4(acc[0] + bias, acc[1] + bias, acc[2] + bias, acc[3] + bias);
      *reinterpret_cast<uint2*>(dst) = __builtin_bit_cast(uint2, pv);
    }
  }
}

// ---------- MFMA flash attention v3: V^T in LDS + depth-4 K software pipeline ----------
// grid = 64 bh * 16 qgroup = 1024 blocks; block = 4 waves, each wave = 16 queries, full 1024 kv.
// V^T LDS stride 1034 shorts (517 banks == 5 mod 32, odd -> conflict-free b32-pair reads).
// K pipeline: 4 frags in flight (use-distance 4 iters ~ 300 cyc > ~200 cyc L2 latency).
__global__ __launch_bounds__(256) void attn_kernel(
    const ushort_t* __restrict__ Qb, const ushort_t* __restrict__ Kb,
    const ushort_t* __restrict__ VT, ushort_t* __restrict__ Ab)
{
  __shared__ ushort_t s_v[16 * 1034];   // 33 KB
  const int tid = threadIdx.x, w = tid >> 6, l = tid & 63, lr = l & 15, lg = l >> 4;
  const int bid = blockIdx.x;
  const int blk = ((bid & 7) << 7) | (bid >> 3);   // XCD-aware bijection (1024 = 8*128)
  const int bh = blk >> 4, qg = blk & 15;
  const int q0 = qg * 64 + w * 16;
  // ---- stage V^T[16][1024] -> s_v[16][1034] (coalesced 16B loads, b32 LDS writes)
  {
    const ushort_t* vsrc = VT + (size_t)bh * 16 * NN;
    #pragma unroll
    for (int i = 0; i < 8; ++i) {
      int idx = i * 2048 + tid * 8;
      int row = idx >> 10, col = idx & 1023;
      uint4 d = *reinterpret_cast<const uint4*>(vsrc + row * NN + col);
      unsigned int* ds = (unsigned int*)&s_v[row * 1034 + col];
      ds[0] = d.x; ds[1] = d.y; ds[2] = d.z; ds[3] = d.w;
    }
  }
  __syncthreads();
  // ---- main sweep
  bf16x4 qf = ldbf4(Qb + ((size_t)bh * NN + q0 + lr) * 16 + 4 * lg);
  const ushort_t* kp = Kb + (size_t)bh * NN * 16 + lr * 16 + 4 * lg;
  const int vbase = lr * 1034 + 4 * lg;
  f32x4 oA = {0.f, 0.f, 0.f, 0.f}, oB = {0.f, 0.f, 0.f, 0.f};
  float psA = 0.f, psB = 0.f;

#define ATTN_STEP(KF, CC, OO, PS) { \
    unsigned int v0_ = *(const unsigned int*)&s_v[vbase + (CC) * 16]; \
    unsigned int v1_ = *(const unsigned int*)&s_v[vbase + (CC) * 16 + 2]; \
    uint2 vu_; vu_.x = v0_; vu_.y = v1_; \
    bf16x4 vf_ = __builtin_bit_cast(bf16x4, vu_); \
    f32x4 z_ = {0.f, 0.f, 0.f, 0.f}; \
    f32x4 st_ = __builtin_amdgcn_mfma_f32_16x16x16bf16_1k(KF, qf, z_, 0, 0, 0); \
    float p0_ = __builtin_amdgcn_exp2f(st_[0]); \
    float p1_ = __builtin_amdgcn_exp2f(st_[1]); \
    float p2_ = __builtin_amdgcn_exp2f(st_[2]); \
    float p3_ = __builtin_amdgcn_exp2f(st_[3]); \
    PS += (p0_ + p1_) + (p2_ + p3_); \
    OO = __builtin_amdgcn_mfma_f32_16x16x16bf16_1k(vf_, pack4(p0_, p1_, p2_, p3_), OO, 0, 0, 0); \
  }

  bf16x4 k0 = ldbf4(kp + 0 * 256);
  bf16x4 k1 = ldbf4(kp + 1 * 256);
  bf16x4 k2 = ldbf4(kp + 2 * 256);
  bf16x4 k3 = ldbf4(kp + 3 * 256);
  for (int c = 0; c < 60; c += 4) {
    bf16x4 n0 = ldbf4(kp + (c + 4) * 256);
    bf16x4 n1 = ldbf4(kp + (c + 5) * 256);
    bf16x4 n2 = ldbf4(kp + (c + 6) * 256);
    bf16x4 n3 = ldbf4(kp + (c + 7) * 256);
    ATTN_STEP(k0, c + 0, oA, psA);
    ATTN_STEP(k1, c + 1, oB, psB);
    ATTN_STEP(k2, c + 2, oA, psA);
    ATTN_STEP(k3, c + 3, oB, psB);
    k0 = n0; k1 = n1; k2 = n2; k3 = n3;
  }
  ATTN_STEP(k0, 60, oA, psA);
  ATTN_STEP(k1, 61, oB, psB);
  ATTN_STEP(k2, 62, oA, psA);
  ATTN_STEP(k3, 63, oB, psB);
#undef ATTN_STEP

  float ps = psA + psB;
  ps += __shfl_xor(ps, 16);
  ps += __shfl_xor(ps, 32);
  float inv = 1.f / ps;
  const int b = bh >> 2, h = bh & 3;
  ushort_t* dst = Ab + ((size_t)b * NN + q0 + lr) * 64 + h * 16 + 4 * lg;
  bf16x4 ov = pack4((oA[0] + oB[0]) * inv, (oA[1] + oB[1]) * inv,
                    (oA[2] + oB[2]) * inv, (oA[3] + oB[3]) * inv);
  *reinterpret_cast<uint2*>(dst) = __builtin_bit_cast(uint2, ov);
}

// ---------- SA1 tail: out-proj + res -> LN -> gelu-F1 -> F2+res -> mid-linear -> LN -> QKV(SA2) ----------
__global__ __launch_bounds__(256) void ffnq_kernel(
    const ushort_t* __restrict__ Ab, const float* __restrict__ Xres,
    const ushort_t* __restrict__ Wo, const float* __restrict__ bo,
    const float* __restrict__ g, const float* __restrict__ beta,
    const ushort_t* __restrict__ W1, const float* __restrict__ b1,
    const ushort_t* __restrict__ W2, const float* __restrict__ b2,
    const ushort_t* __restrict__ Wt, const float* __restrict__ bt,
    const float* __restrict__ temb2,
    const float* __restrict__ g2, const float* __restrict__ beta2,
    const ushort_t* __restrict__ Wq, const float* __restrict__ bq,
    float* __restrict__ X2,
    ushort_t* __restrict__ Qb, ushort_t* __restrict__ Kb, ushort_t* __restrict__ VT)
{
  __shared__ ushort_t s_b1[32 * 68];
  __shared__ ushort_t s_b2[32 * 68];
  __shared__ float s_av[32 * 66];
  __shared__ float s_rs[32 * 66];
  const int tid = threadIdx.x;
  const int m0 = blockIdx.x * 32, b = m0 >> 10;
  const int r = tid >> 3, c0 = (tid & 7) * 8;
  {
    const uint2* ai = (const uint2*)(Ab + (size_t)(m0 + r) * 64 + c0);
    uint2* ao = (uint2*)&s_b1[r * 68 + c0];
    ao[0] = ai[0]; ao[1] = ai[1];
    const float4* xi = (const float4*)(Xres + (size_t)(m0 + r) * 64 + c0);
    float4* xo = (float4*)&s_rs[r * 66 + c0];
    xo[0] = xi[0]; xo[1] = xi[1];
  }
  __syncthreads();
  const int w = tid >> 6, l = tid & 63, lr = l & 15, lg = l >> 4;
  const int rowoff = (w & 1) * 16, jt0 = (w >> 1) * 2;
  // G1: av = A @ Wo^T + bo + Xres -> s_av
  {
    Frag af = ldA(s_b1, rowoff + lr, lg);
    #pragma unroll
    for (int jtl = 0; jtl < 2; ++jtl) {
      int jt = jt0 + jtl;
      f32x4 acc = gemmW(af, Wo, jt * 16 + lr, lg);
      float bias = bo[jt * 16 + lr];
      #pragma unroll
      for (int rr = 0; rr < 4; ++rr) {
        int m = rowoff + 4 * lg + rr;
        s_av[m * 66 + jt * 16 + lr] = acc[rr] + bias + s_rs[m * 66 + jt * 16 + lr];
      }
    }
  }
  __syncthreads();
  ln_stage(s_av, s_b1, g, beta, tid);
  __syncthreads();
  // G2: gelu(h @ W1^T + b1) -> s_b2
  {
    Frag af = ldA(s_b1, rowoff + lr, lg);
    #pragma unroll
    for (int jtl = 0; jtl < 2; ++jtl) {
      int jt = jt0 + jtl;
      f32x4 acc = gemmW(af, W1, jt * 16 + lr, lg);
      float bias = b1[jt * 16 + lr];
      #pragma unroll
      for (int rr = 0; rr < 4; ++rr) {
        float t = acc[rr] + bias;
        t = 0.5f * t * (1.f + erff(t * 0.70710678118f));
        s_b2[(rowoff + 4 * lg + rr) * 68 + jt * 16 + lr] = f2bf(t);
      }
    }
  }
  __syncthreads();
  // G3: xnew = h1 @ W2^T + b2 + av; store relu(xnew) bf16 -> s_b1
  {
    Frag af = ldA(s_b2, rowoff + lr, lg);
    #pragma unroll
    for (int jtl = 0; jtl < 2; ++jtl) {
      int jt = jt0 + jtl;
      f32x4 acc = gemmW(af, W2, jt * 16 + lr, lg);
      float bias = b2[jt * 16 + lr];
      #pragma unroll
      for (int rr = 0; rr < 4; ++rr) {
        int m = rowoff + 4 * lg + rr;
        float sa = acc[rr] + bias + s_av[m * 66 + jt * 16 + lr];
        s_b1[m * 68 + jt * 16 + lr] = f2bf(fmaxf(sa, 0.f));
      }
    }
  }
  __syncthreads();
  // G4: X2 = relu(xnew) @ Wmid^T + bmid + temb2 -> global + s_av
  {
    Frag af = ldA(s_b1, rowoff + lr, lg);
    #pragma unroll
    for (int jtl = 0; jtl < 2; ++jtl) {
      int jt = jt0 + jtl;
      f32x4 acc = gemmW(af, Wt, jt * 16 + lr, lg);
      float bias = bt[jt * 16 + lr] + temb2[b * EE + jt * 16 + lr];
      #pragma unroll
      for (int rr = 0; rr < 4; ++rr) {
        int m = rowoff + 4 * lg + rr;
        float x2 = acc[rr] + bias;
        s_av[m * 66 + jt * 16 + lr] = x2;
        X2[(size_t)(m0 + m) * 64 + jt * 16 + lr] = x2;
      }
    }
  }
  __syncthreads();
  ln_stage(s_av, s_b1, g2, beta2, tid);
  __syncthreads();
  // G5: QKV projection for SA2
  {
    Frag af = ldA(s_b1, rowoff + lr, lg);
    const int jq0 = (w >> 1) * 6;
    const int q0s = (m0 & 1023) + rowoff + 4 * lg;
    #pragma unroll
    for (int jtl = 0; jtl < 6; ++jtl) {
      int jt = jq0 + jtl;
      f32x4 acc = gemmW(af, Wq, jt * 16 + lr, lg);
      float bias = bq[jt * 16 + lr];
      if (jt < 4) {
        ushort_t* dst = Qb + ((size_t)(b * NH + jt) * NN + q0s) * 16 + lr;
        #pragma unroll
        for (int rr = 0; rr < 4; ++rr) dst[rr * 16] = f2bf((acc[rr] + bias) * QSCALE);
      } else if (jt < 8) {
        ushort_t* dst = Kb + ((size_t)(b * NH + jt - 4) * NN + q0s) * 16 + lr;
        #pragma unroll
        for (int rr = 0; rr < 4; ++rr) dst[rr * 16] = f2bf(acc[rr] + bias);
      } else {
        ushort_t* dst = VT + ((size_t)(b * NH + jt - 8) * 16 + lr) * NN + q0s;
        bf16x4 pv = pack4(acc[0] + bias, acc[1] + bias, acc[2] + bias, acc[3] + bias);
        *reinterpret_cast<uint2*>(dst) = __builtin_bit_cast(uint2, pv);
      }
    }
  }
}

// ---------- SA2 tail: out-proj + res -> LN -> gelu-F1 -> F2+res -> final 3-col * mask ----------
__global__ __launch_bounds__(256) void ffn_final_kernel(
    const ushort_t* __restrict__ Ab, const float* __restrict__ Xres,
    const ushort_t* __restrict__ Wo, const float* __restrict__ bo,
    const float* __restrict__ g, const float* __restrict__ beta,
    const ushort_t* __restrict__ W1, const float* __restrict__ b1,
    const ushort_t* __restrict__ W2, const float* __restrict__ b2,
    const float* __restrict__ wout3, const float* __restrict__ bout3,
    const float* __restrict__ mask,
    float* __restrict__ Out)
{
  __shared__ ushort_t s_b1[32 * 68];
  __shared__ ushort_t s_b2[32 * 68];
  __shared__ float s_av[32 * 66];
  __shared__ float s_rs[32 * 66];
  const int tid = threadIdx.x;
  const int m0 = blockIdx.x * 32;
  const int r = tid >> 3, c0 = (tid & 7) * 8;
  {
    const uint2* ai = (const uint2*)(Ab + (size_t)(m0 + r) * 64 + c0);
    uint2* ao = (uint2*)&s_b1[r * 68 + c0];
    ao[0] = ai[0]; ao[1] = ai[1];
    const float4* xi = (const float4*)(Xres + (size_t)(m0 + r) * 64 + c0);
    float4* xo = (float4*)&s_rs[r * 66 + c0];
    xo[0] = xi[0]; xo[1] = xi[1];
  }
  __syncthreads();
  const int w = tid >> 6, l = tid & 63, lr = l & 15, lg = l >> 4;
  const int rowoff = (w & 1) * 16, jt0 = (w >> 1) * 2;
  {
    Frag af = ldA(s_b1, rowoff + lr, lg);
    #pragma unroll
    for (int jtl = 0; jtl < 2; ++jtl) {
      int jt = jt0 + jtl;
      f32x4 acc = gemmW(af, Wo, jt * 16 + lr, lg);
      float bias = bo[jt * 16 + lr];
      #pragma unroll
      for (int rr = 0; rr < 4; ++rr) {
        int m = rowoff + 4 * lg + rr;
        s_av[m * 66 + jt * 16 + lr] = acc[rr] + bias + s_rs[m * 66 + jt * 16 + lr];
      }
    }
  }
  __syncthreads();
  ln_stage(s_av, s_b1, g, beta, tid);
  __syncthreads();
  {
    Frag af = ldA(s_b1, rowoff + lr, lg);
    #pragma unroll
    for (int jtl = 0; jtl < 2; ++jtl) {
      int jt = jt0 + jtl;
      f32x4 acc = gemmW(af, W1, jt * 16 + lr, lg);
      float bias = b1[jt * 16 + lr];
      #pragma unroll
      for (int rr = 0; rr < 4; ++rr) {
        float t = acc[rr] + bias;
        t = 0.5f * t * (1.f + erff(t * 0.70710678118f));
        s_b2[(rowoff + 4 * lg + rr) * 68 + jt * 16 + lr] = f2bf(t);
      }
    }
  }
  __syncthreads();
  {
    Frag af = ldA(s_b2, rowoff + lr, lg);
    #pragma unroll
    for (int jtl = 0; jtl < 2; ++jtl) {
      int jt = jt0 + jtl;
      f32x4 acc = gemmW(af, W2, jt * 16 + lr, lg);
      float bias = b2[jt * 16 + lr];
      #pragma unroll
      for (int rr = 0; rr < 4; ++rr) {
        int m = rowoff + 4 * lg + rr;
        s_rs[m * 66 + jt * 16 + lr] = acc[rr] + bias + s_av[m * 66 + jt * 16 + lr];
      }
    }
  }
  __syncthreads();
  if (tid < 96) {
    int row = tid / 3, c = tid - row * 3;
    float acc = bout3[c];
    #pragma unroll 8
    for (int k = 0; k < 64; ++k)
      acc = fmaf(fmaxf(s_rs[row * 66 + k], 0.f), wout3[c * 64 + k], acc);
    Out[(size_t)(m0 + row) * 3 + c] = acc * mask[m0 + row];
  }
}

// ---------- host ----------
extern "C" void kernel_launch(void* const* d_in, const int* in_sizes, int n_in,
                              void* d_out, int out_size, void* d_ws, size_t ws_size,
                              hipStream_t stream)
{
  const float* pos    = (const float*)d_in[0];
  const float* t_int  = (const float*)d_in[1];
  const float* nmask  = (const float*)d_in[2];
  const float* w_in   = (const float*)d_in[3];
  const float* b_in   = (const float*)d_in[4];
  const float* w_mid  = (const float*)d_in[5];
  const float* b_mid  = (const float*)d_in[6];
  const float* w_out  = (const float*)d_in[7];
  const float* b_out  = (const float*)d_in[8];
  const float* e1w    = (const float*)d_in[9];
  const float* e1b    = (const float*)d_in[10];
  const float* e2w    = (const float*)d_in[11];
  const float* e2b    = (const float*)d_in[12];
  const float* const* SA1 = (const float* const*)(d_in + 13);
  const float* const* SA2 = (const float* const*)(d_in + 25);

  float* ws    = (float*)d_ws;
  float* temb1 = ws;
  float* temb2 = ws + 1024;
  float* X     = ws + 2048;
  float* X2    = X + (size_t)M_TOT * 64;
  ushort_t* ub = (ushort_t*)(X2 + (size_t)M_TOT * 64);
  ushort_t* Qb = ub;
  ushort_t* Kb = Qb + (size_t)BB * NH * NN * 16;
  ushort_t* VT = Kb + (size_t)BB * NH * NN * 16;
  ushort_t* Ab = VT + (size_t)BB * NH * NN * 16;
  ushort_t* Wb = Ab + (size_t)M_TOT * 64;
  ushort_t* Wqkv1 = Wb;
  ushort_t* Wo1   = Wb + 12288;
  ushort_t* W1_1  = Wb + 16384;
  ushort_t* W2_1  = Wb + 20480;
  ushort_t* Wqkv2 = Wb + 24576;
  ushort_t* Wo2   = Wb + 36864;
  ushort_t* W1_2  = Wb + 40960;
  ushort_t* W2_2  = Wb + 45056;
  ushort_t* Wmid  = Wb + 49152;

  prep_kernel<<<dim3(16, 10), 256, 0, stream>>>(
      SA1[2], SA1[4], SA1[8], SA1[10], SA2[2], SA2[4], SA2[8], SA2[10], w_mid, Wb,
      t_int, e1w, e1b, e2w, e2b, temb1, temb2);

  qkv1_kernel<<<M_TOT / 32, 256, 0, stream>>>(
      pos, w_in, b_in, temb1, X, SA1[0], SA1[1], Wqkv1, SA1[3], Qb, Kb, VT);
  attn_kernel<<<BB * NH * 16, 256, 0, stream>>>(Qb, Kb, VT, Ab);
  ffnq_kernel<<<M_TOT / 32, 256, 0, stream>>>(
      Ab, X, Wo1, SA1[5], SA1[6], SA1[7], W1_1, SA1[9], W2_1, SA1[11],
      Wmid, b_mid, temb2, SA2[0], SA2[1], Wqkv2, SA2[3], X2, Qb, Kb, VT);
  attn_kernel<<<BB * NH * 16, 256, 0, stream>>>(Qb, Kb, VT, Ab);
  ffn_final_kernel<<<M_TOT / 32, 256, 0, stream>>>(
      Ab, X2, Wo2, SA2[5], SA2[6], SA2[7], W1_2, SA2[9], W2_2, SA2[11],
      w_out, b_out, nmask, (float*)d_out);
}

// Round 13
// 79.732 us; speedup vs baseline: 17.3920x; 1.0013x over previous
//
#include <hip/hip_runtime.h>
#include <hip/hip_bf16.h>
#include <math.h>

// SimpleFC: B=16, N=1024, E=64, H=4, dh=16.
#define NH 4
#define EE 64
#define BB 16
#define NN 1024
#define M_TOT (BB * NN)
#define QSCALE 0.3606737602222409f   // 0.25 * log2(e)

typedef short bf16x4 __attribute__((ext_vector_type(4)));
typedef float f32x4 __attribute__((ext_vector_type(4)));
typedef unsigned short ushort_t;

// ---------- helpers (R4-proven) ----------
__device__ __forceinline__ unsigned int cvt_pk_bf16(float a, float b) {
  unsigned int r;
  asm("v_cvt_pk_bf16_f32 %0, %1, %2" : "=v"(r) : "v"(a), "v"(b));
  return r;
}
__device__ __forceinline__ ushort_t f2bf(float v) { return (ushort_t)cvt_pk_bf16(v, v); }
__device__ __forceinline__ bf16x4 pack4(float a, float b, float c, float d) {
  uint2 u; u.x = cvt_pk_bf16(a, b); u.y = cvt_pk_bf16(c, d);
  return __builtin_bit_cast(bf16x4, u);
}
__device__ __forceinline__ bf16x4 ldbf4(const ushort_t* p) {
  return __builtin_bit_cast(bf16x4, *reinterpret_cast<const uint2*>(p));
}

struct Frag { bf16x4 a[4]; };
__device__ __forceinline__ Frag ldA(const ushort_t* s, int row, int lg) {
  Frag f;
  #pragma unroll
  for (int kb = 0; kb < 4; ++kb) f.a[kb] = ldbf4(s + row * 68 + kb * 16 + 4 * lg);
  return f;
}
__device__ __forceinline__ f32x4 gemmW(const Frag& f, const ushort_t* W, int jcol, int lg) {
  f32x4 acc = {0.f, 0.f, 0.f, 0.f};
  const ushort_t* wb = W + jcol * 64 + 4 * lg;
  #pragma unroll
  for (int kb = 0; kb < 4; ++kb)
    acc = __builtin_amdgcn_mfma_f32_16x16x16bf16_1k(f.a[kb], ldbf4(wb + kb * 16), acc, 0, 0, 0);
  return acc;
}
// LN a 32x64 f32 LDS tile (stride 66) -> bf16 LDS tile (stride 68). 8 threads/row. (R4-proven)
__device__ __forceinline__ void ln_stage(const float* s_src, ushort_t* s_dst,
    const float* __restrict__ g, const float* __restrict__ beta, int tid) {
  int r = tid >> 3, c0 = (tid & 7) * 8;
  float v[8];
  #pragma unroll
  for (int j = 0; j < 8; ++j) v[j] = s_src[r * 66 + c0 + j];
  float s = 0.f;
  #pragma unroll
  for (int j = 0; j < 8; ++j) s += v[j];
  s += __shfl_xor(s, 1); s += __shfl_xor(s, 2); s += __shfl_xor(s, 4);
  float mean = s * (1.f / EE);
  float qv = 0.f;
  #pragma unroll
  for (int j = 0; j < 8; ++j) { float d = v[j] - mean; qv += d * d; }
  qv += __shfl_xor(qv, 1); qv += __shfl_xor(qv, 2); qv += __shfl_xor(qv, 4);
  float rs = rsqrtf(qv * (1.f / EE) + 1e-5f);
  unsigned int* dst = (unsigned int*)(s_dst + r * 68 + c0);
  #pragma unroll
  for (int j = 0; j < 4; ++j) {
    float h0 = (v[2*j]   - mean) * rs * g[c0 + 2*j]   + beta[c0 + 2*j];
    float h1 = (v[2*j+1] - mean) * rs * g[c0 + 2*j+1] + beta[c0 + 2*j+1];
    dst[j] = cvt_pk_bf16(h0, h1);
  }
}

// ---------- prep: weight f32->bf16 (y<9) + timestep embedding (y==9) ----------
__global__ __launch_bounds__(256) void prep_kernel(
    const float* a0, const float* a1, const float* a2, const float* a3,
    const float* a4, const float* a5, const float* a6, const float* a7,
    const float* a8, ushort_t* __restrict__ dst,
    const float* __restrict__ t_int,
    const float* __restrict__ e1w, const float* __restrict__ e1b,
    const float* __restrict__ e2w, const float* __restrict__ e2b,
    float* __restrict__ temb1, float* __restrict__ temb2)
{
  if (blockIdx.y < 9) {
    const int off[9] = {0, 12288, 16384, 20480, 24576, 36864, 40960, 45056, 49152};
    const int sz[9]  = {12288, 4096, 4096, 4096, 12288, 4096, 4096, 4096, 4096};
    const float* srcs[9] = {a0, a1, a2, a3, a4, a5, a6, a7, a8};
    int s = blockIdx.y;
    const float* src = srcs[s];
    for (int i = blockIdx.x * 256 + threadIdx.x; i < sz[s]; i += 16 * 256)
      dst[off[s] + i] = f2bf(src[i]);
    return;
  }
  __shared__ float s_silu[EE];
  int b = blockIdx.x, e = threadIdx.x;
  if (e >= 64) return;
  float t = t_int[b];
  int i = e & 31;
  float inv_freq = powf(10000.f, -(float)(2 * i) / (float)EE);
  float ang = t * inv_freq;
  float ti = (e < 32) ? sinf(ang) : cosf(ang);
  s_silu[e] = ti / (1.f + expf(-ti));
  __syncthreads();
  float v1 = e1b[e], v2 = e2b[e];
  #pragma unroll 8
  for (int k = 0; k < EE; ++k) {
    float s = s_silu[k];
    v1 = fmaf(s, e1w[e * EE + k], v1);
    v2 = fmaf(s, e2w[e * EE + k], v2);
  }
  temb1[b * EE + e] = v1;
  temb2[b * EE + e] = v2;
}

// ---------- xinit + LN + QKV projection (SA1 entry). 32-row tile, col-split waves ----------
__global__ __launch_bounds__(256) void qkv1_kernel(
    const float* __restrict__ pos,
    const float* __restrict__ w_in, const float* __restrict__ b_in,
    const float* __restrict__ temb1, float* __restrict__ Xout,
    const float* __restrict__ g, const float* __restrict__ beta,
    const ushort_t* __restrict__ Wq, const float* __restrict__ bq,
    ushort_t* __restrict__ Qb, ushort_t* __restrict__ Kb, ushort_t* __restrict__ VT)
{
  __shared__ ushort_t s_h[32 * 68];
  const int tid = threadIdx.x;
  const int m0 = blockIdx.x * 32;
  const int b = m0 >> 10;
  const int r = tid >> 3, c0 = (tid & 7) * 8;
  float v[8];
  {
    const float* pr = pos + (size_t)(m0 + r) * 3;
    float p0 = pr[0], p1 = pr[1], p2 = pr[2];
    #pragma unroll
    for (int j = 0; j < 8; ++j) {
      int c = c0 + j;
      float t = b_in[c] + temb1[b * EE + c];
      t = fmaf(p0, w_in[c * 3 + 0], t);
      t = fmaf(p1, w_in[c * 3 + 1], t);
      t = fmaf(p2, w_in[c * 3 + 2], t);
      v[j] = t;
    }
    float4* xo = (float4*)(Xout + (size_t)(m0 + r) * 64 + c0);
    float4 t4a = {v[0], v[1], v[2], v[3]}, t4b = {v[4], v[5], v[6], v[7]};
    xo[0] = t4a; xo[1] = t4b;
  }
  float s = 0.f;
  #pragma unroll
  for (int j = 0; j < 8; ++j) s += v[j];
  s += __shfl_xor(s, 1); s += __shfl_xor(s, 2); s += __shfl_xor(s, 4);
  float mean = s * (1.f / EE);
  float qv = 0.f;
  #pragma unroll
  for (int j = 0; j < 8; ++j) { float d = v[j] - mean; qv += d * d; }
  qv += __shfl_xor(qv, 1); qv += __shfl_xor(qv, 2); qv += __shfl_xor(qv, 4);
  float rs = rsqrtf(qv * (1.f / EE) + 1e-5f);
  {
    unsigned int* sh = (unsigned int*)&s_h[r * 68 + c0];
    #pragma unroll
    for (int j = 0; j < 4; ++j) {
      float h0 = (v[2*j]   - mean) * rs * g[c0 + 2*j]   + beta[c0 + 2*j];
      float h1 = (v[2*j+1] - mean) * rs * g[c0 + 2*j+1] + beta[c0 + 2*j+1];
      sh[j] = cvt_pk_bf16(h0, h1);
    }
  }
  __syncthreads();
  const int w = tid >> 6, l = tid & 63, lr = l & 15, lg = l >> 4;
  const int rowoff = (w & 1) * 16, jt0 = (w >> 1) * 6;
  Frag af = ldA(s_h, rowoff + lr, lg);
  const int q0s = (m0 & 1023) + rowoff + 4 * lg;
  #pragma unroll
  for (int jtl = 0; jtl < 6; ++jtl) {
    int jt = jt0 + jtl;
    f32x4 acc = gemmW(af, Wq, jt * 16 + lr, lg);
    float bias = bq[jt * 16 + lr];
    if (jt < 4) {
      ushort_t* dst = Qb + ((size_t)(b * NH + jt) * NN + q0s) * 16 + lr;
      #pragma unroll
      for (int rr = 0; rr < 4; ++rr) dst[rr * 16] = f2bf((acc[rr] + bias) * QSCALE);
    } else if (jt < 8) {
      ushort_t* dst = Kb + ((size_t)(b * NH + jt - 4) * NN + q0s) * 16 + lr;
      #pragma unroll
      for (int rr = 0; rr < 4; ++rr) dst[rr * 16] = f2bf(acc[rr] + bias);
    } else {
      ushort_t* dst = VT + ((size_t)(b * NH + jt - 8) * 16 + lr) * NN + q0s;
      bf16x4 pv = pack4(acc[0] + bias, acc[1] + bias, acc[2] + bias, acc[3] + bias);
      *reinterpret_cast<uint2*>(dst) = __builtin_bit_cast(uint2, pv);
    }
  }
}

// ---------- MFMA flash attention v3 (R9-frozen): V^T in LDS + depth-4 K software pipeline ----------
// grid = 64 bh * 16 qgroup = 1024 blocks; block = 4 waves, each wave = 16 queries, full 1024 kv.
// V^T LDS stride 1034 shorts (517 banks == 5 mod 32, odd -> conflict-free b32-pair reads).
// FROZEN: R10 (ring), R11 (depth-8), R12 (8-wave) all miscompiled despite semantic equivalence.
__global__ __launch_bounds__(256) void attn_kernel(
    const ushort_t* __restrict__ Qb, const ushort_t* __restrict__ Kb,
    const ushort_t* __restrict__ VT, ushort_t* __restrict__ Ab)
{
  __shared__ ushort_t s_v[16 * 1034];   // 33 KB
  const int tid = threadIdx.x, w = tid >> 6, l = tid & 63, lr = l & 15, lg = l >> 4;
  const int bid = blockIdx.x;
  const int blk = ((bid & 7) << 7) | (bid >> 3);   // XCD-aware bijection (1024 = 8*128)
  const int bh = blk >> 4, qg = blk & 15;
  const int q0 = qg * 64 + w * 16;
  // ---- stage V^T[16][1024] -> s_v[16][1034] (coalesced 16B loads, b32 LDS writes)
  {
    const ushort_t* vsrc = VT + (size_t)bh * 16 * NN;
    #pragma unroll
    for (int i = 0; i < 8; ++i) {
      int idx = i * 2048 + tid * 8;
      int row = idx >> 10, col = idx & 1023;
      uint4 d = *reinterpret_cast<const uint4*>(vsrc + row * NN + col);
      unsigned int* ds = (unsigned int*)&s_v[row * 1034 + col];
      ds[0] = d.x; ds[1] = d.y; ds[2] = d.z; ds[3] = d.w;
    }
  }
  __syncthreads();
  // ---- main sweep
  bf16x4 qf = ldbf4(Qb + ((size_t)bh * NN + q0 + lr) * 16 + 4 * lg);
  const ushort_t* kp = Kb + (size_t)bh * NN * 16 + lr * 16 + 4 * lg;
  const int vbase = lr * 1034 + 4 * lg;
  f32x4 oA = {0.f, 0.f, 0.f, 0.f}, oB = {0.f, 0.f, 0.f, 0.f};
  float psA = 0.f, psB = 0.f;

#define ATTN_STEP(KF, CC, OO, PS) { \
    unsigned int v0_ = *(const unsigned int*)&s_v[vbase + (CC) * 16]; \
    unsigned int v1_ = *(const unsigned int*)&s_v[vbase + (CC) * 16 + 2]; \
    uint2 vu_; vu_.x = v0_; vu_.y = v1_; \
    bf16x4 vf_ = __builtin_bit_cast(bf16x4, vu_); \
    f32x4 z_ = {0.f, 0.f, 0.f, 0.f}; \
    f32x4 st_ = __builtin_amdgcn_mfma_f32_16x16x16bf16_1k(KF, qf, z_, 0, 0, 0); \
    float p0_ = __builtin_amdgcn_exp2f(st_[0]); \
    float p1_ = __builtin_amdgcn_exp2f(st_[1]); \
    float p2_ = __builtin_amdgcn_exp2f(st_[2]); \
    float p3_ = __builtin_amdgcn_exp2f(st_[3]); \
    PS += (p0_ + p1_) + (p2_ + p3_); \
    OO = __builtin_amdgcn_mfma_f32_16x16x16bf16_1k(vf_, pack4(p0_, p1_, p2_, p3_), OO, 0, 0, 0); \
  }

  bf16x4 k0 = ldbf4(kp + 0 * 256);
  bf16x4 k1 = ldbf4(kp + 1 * 256);
  bf16x4 k2 = ldbf4(kp + 2 * 256);
  bf16x4 k3 = ldbf4(kp + 3 * 256);
  for (int c = 0; c < 60; c += 4) {
    bf16x4 n0 = ldbf4(kp + (c + 4) * 256);
    bf16x4 n1 = ldbf4(kp + (c + 5) * 256);
    bf16x4 n2 = ldbf4(kp + (c + 6) * 256);
    bf16x4 n3 = ldbf4(kp + (c + 7) * 256);
    ATTN_STEP(k0, c + 0, oA, psA);
    ATTN_STEP(k1, c + 1, oB, psB);
    ATTN_STEP(k2, c + 2, oA, psA);
    ATTN_STEP(k3, c + 3, oB, psB);
    k0 = n0; k1 = n1; k2 = n2; k3 = n3;
  }
  ATTN_STEP(k0, 60, oA, psA);
  ATTN_STEP(k1, 61, oB, psB);
  ATTN_STEP(k2, 62, oA, psA);
  ATTN_STEP(k3, 63, oB, psB);
#undef ATTN_STEP

  float ps = psA + psB;
  ps += __shfl_xor(ps, 16);
  ps += __shfl_xor(ps, 32);
  float inv = 1.f / ps;
  const int b = bh >> 2, h = bh & 3;
  ushort_t* dst = Ab + ((size_t)b * NN + q0 + lr) * 64 + h * 16 + 4 * lg;
  bf16x4 ov = pack4((oA[0] + oB[0]) * inv, (oA[1] + oB[1]) * inv,
                    (oA[2] + oB[2]) * inv, (oA[3] + oB[3]) * inv);
  *reinterpret_cast<uint2*>(dst) = __builtin_bit_cast(uint2, ov);
}

// ---------- SA1 tail: out-proj + res -> LN -> gelu-F1 -> F2+res -> mid-linear -> LN -> QKV(SA2) ----------
__global__ __launch_bounds__(256) void ffnq_kernel(
    const ushort_t* __restrict__ Ab, const float* __restrict__ Xres,
    const ushort_t* __restrict__ Wo, const float* __restrict__ bo,
    const float* __restrict__ g, const float* __restrict__ beta,
    const ushort_t* __restrict__ W1, const float* __restrict__ b1,
    const ushort_t* __restrict__ W2, const float* __restrict__ b2,
    const ushort_t* __restrict__ Wt, const float* __restrict__ bt,
    const float* __restrict__ temb2,
    const float* __restrict__ g2, const float* __restrict__ beta2,
    const ushort_t* __restrict__ Wq, const float* __restrict__ bq,
    float* __restrict__ X2,
    ushort_t* __restrict__ Qb, ushort_t* __restrict__ Kb, ushort_t* __restrict__ VT)
{
  __shared__ ushort_t s_b1[32 * 68];
  __shared__ ushort_t s_b2[32 * 68];
  __shared__ float s_av[32 * 66];
  __shared__ float s_rs[32 * 66];
  const int tid = threadIdx.x;
  const int m0 = blockIdx.x * 32, b = m0 >> 10;
  const int r = tid >> 3, c0 = (tid & 7) * 8;
  {
    const uint2* ai = (const uint2*)(Ab + (size_t)(m0 + r) * 64 + c0);
    uint2* ao = (uint2*)&s_b1[r * 68 + c0];
    ao[0] = ai[0]; ao[1] = ai[1];
    const float4* xi = (const float4*)(Xres + (size_t)(m0 + r) * 64 + c0);
    float4* xo = (float4*)&s_rs[r * 66 + c0];
    xo[0] = xi[0]; xo[1] = xi[1];
  }
  __syncthreads();
  const int w = tid >> 6, l = tid & 63, lr = l & 15, lg = l >> 4;
  const int rowoff = (w & 1) * 16, jt0 = (w >> 1) * 2;
  // G1: av = A @ Wo^T + bo + Xres -> s_av
  {
    Frag af = ldA(s_b1, rowoff + lr, lg);
    #pragma unroll
    for (int jtl = 0; jtl < 2; ++jtl) {
      int jt = jt0 + jtl;
      f32x4 acc = gemmW(af, Wo, jt * 16 + lr, lg);
      float bias = bo[jt * 16 + lr];
      #pragma unroll
      for (int rr = 0; rr < 4; ++rr) {
        int m = rowoff + 4 * lg + rr;
        s_av[m * 66 + jt * 16 + lr] = acc[rr] + bias + s_rs[m * 66 + jt * 16 + lr];
      }
    }
  }
  __syncthreads();
  ln_stage(s_av, s_b1, g, beta, tid);
  __syncthreads();
  // G2: gelu(h @ W1^T + b1) -> s_b2
  {
    Frag af = ldA(s_b1, rowoff + lr, lg);
    #pragma unroll
    for (int jtl = 0; jtl < 2; ++jtl) {
      int jt = jt0 + jtl;
      f32x4 acc = gemmW(af, W1, jt * 16 + lr, lg);
      float bias = b1[jt * 16 + lr];
      #pragma unroll
      for (int rr = 0; rr < 4; ++rr) {
        float t = acc[rr] + bias;
        t = 0.5f * t * (1.f + erff(t * 0.70710678118f));
        s_b2[(rowoff + 4 * lg + rr) * 68 + jt * 16 + lr] = f2bf(t);
      }
    }
  }
  __syncthreads();
  // G3: xnew = h1 @ W2^T + b2 + av; store relu(xnew) bf16 -> s_b1
  {
    Frag af = ldA(s_b2, rowoff + lr, lg);
    #pragma unroll
    for (int jtl = 0; jtl < 2; ++jtl) {
      int jt = jt0 + jtl;
      f32x4 acc = gemmW(af, W2, jt * 16 + lr, lg);
      float bias = b2[jt * 16 + lr];
      #pragma unroll
      for (int rr = 0; rr < 4; ++rr) {
        int m = rowoff + 4 * lg + rr;
        float sa = acc[rr] + bias + s_av[m * 66 + jt * 16 + lr];
        s_b1[m * 68 + jt * 16 + lr] = f2bf(fmaxf(sa, 0.f));
      }
    }
  }
  __syncthreads();
  // G4: X2 = relu(xnew) @ Wmid^T + bmid + temb2 -> global + s_av
  {
    Frag af = ldA(s_b1, rowoff + lr, lg);
    #pragma unroll
    for (int jtl = 0; jtl < 2; ++jtl) {
      int jt = jt0 + jtl;
      f32x4 acc = gemmW(af, Wt, jt * 16 + lr, lg);
      float bias = bt[jt * 16 + lr] + temb2[b * EE + jt * 16 + lr];
      #pragma unroll
      for (int rr = 0; rr < 4; ++rr) {
        int m = rowoff + 4 * lg + rr;
        float x2 = acc[rr] + bias;
        s_av[m * 66 + jt * 16 + lr] = x2;
        X2[(size_t)(m0 + m) * 64 + jt * 16 + lr] = x2;
      }
    }
  }
  __syncthreads();
  ln_stage(s_av, s_b1, g2, beta2, tid);
  __syncthreads();
  // G5: QKV projection for SA2
  {
    Frag af = ldA(s_b1, rowoff + lr, lg);
    const int jq0 = (w >> 1) * 6;
    const int q0s = (m0 & 1023) + rowoff + 4 * lg;
    #pragma unroll
    for (int jtl = 0; jtl < 6; ++jtl) {
      int jt = jq0 + jtl;
      f32x4 acc = gemmW(af, Wq, jt * 16 + lr, lg);
      float bias = bq[jt * 16 + lr];
      if (jt < 4) {
        ushort_t* dst = Qb + ((size_t)(b * NH + jt) * NN + q0s) * 16 + lr;
        #pragma unroll
        for (int rr = 0; rr < 4; ++rr) dst[rr * 16] = f2bf((acc[rr] + bias) * QSCALE);
      } else if (jt < 8) {
        ushort_t* dst = Kb + ((size_t)(b * NH + jt - 4) * NN + q0s) * 16 + lr;
        #pragma unroll
        for (int rr = 0; rr < 4; ++rr) dst[rr * 16] = f2bf(acc[rr] + bias);
      } else {
        ushort_t* dst = VT + ((size_t)(b * NH + jt - 8) * 16 + lr) * NN + q0s;
        bf16x4 pv = pack4(acc[0] + bias, acc[1] + bias, acc[2] + bias, acc[3] + bias);
        *reinterpret_cast<uint2*>(dst) = __builtin_bit_cast(uint2, pv);
      }
    }
  }
}

// ---------- SA2 tail: out-proj + res -> LN -> gelu-F1 -> F2+res -> final 3-col * mask ----------
__global__ __launch_bounds__(256) void ffn_final_kernel(
    const ushort_t* __restrict__ Ab, const float* __restrict__ Xres,
    const ushort_t* __restrict__ Wo, const float* __restrict__ bo,
    const float* __restrict__ g, const float* __restrict__ beta,
    const ushort_t* __restrict__ W1, const float* __restrict__ b1,
    const ushort_t* __restrict__ W2, const float* __restrict__ b2,
    const float* __restrict__ wout3, const float* __restrict__ bout3,
    const float* __restrict__ mask,
    float* __restrict__ Out)
{
  __shared__ ushort_t s_b1[32 * 68];
  __shared__ ushort_t s_b2[32 * 68];
  __shared__ float s_av[32 * 66];
  __shared__ float s_rs[32 * 66];
  const int tid = threadIdx.x;
  const int m0 = blockIdx.x * 32;
  const int r = tid >> 3, c0 = (tid & 7) * 8;
  {
    const uint2* ai = (const uint2*)(Ab + (size_t)(m0 + r) * 64 + c0);
    uint2* ao = (uint2*)&s_b1[r * 68 + c0];
    ao[0] = ai[0]; ao[1] = ai[1];
    const float4* xi = (const float4*)(Xres + (size_t)(m0 + r) * 64 + c0);
    float4* xo = (float4*)&s_rs[r * 66 + c0];
    xo[0] = xi[0]; xo[1] = xi[1];
  }
  __syncthreads();
  const int w = tid >> 6, l = tid & 63, lr = l & 15, lg = l >> 4;
  const int rowoff = (w & 1) * 16, jt0 = (w >> 1) * 2;
  {
    Frag af = ldA(s_b1, rowoff + lr, lg);
    #pragma unroll
    for (int jtl = 0; jtl < 2; ++jtl) {
      int jt = jt0 + jtl;
      f32x4 acc = gemmW(af, Wo, jt * 16 + lr, lg);
      float bias = bo[jt * 16 + lr];
      #pragma unroll
      for (int rr = 0; rr < 4; ++rr) {
        int m = rowoff + 4 * lg + rr;
        s_av[m * 66 + jt * 16 + lr] = acc[rr] + bias + s_rs[m * 66 + jt * 16 + lr];
      }
    }
  }
  __syncthreads();
  ln_stage(s_av, s_b1, g, beta, tid);
  __syncthreads();
  {
    Frag af = ldA(s_b1, rowoff + lr, lg);
    #pragma unroll
    for (int jtl = 0; jtl < 2; ++jtl) {
      int jt = jt0 + jtl;
      f32x4 acc = gemmW(af, W1, jt * 16 + lr, lg);
      float bias = b1[jt * 16 + lr];
      #pragma unroll
      for (int rr = 0; rr < 4; ++rr) {
        float t = acc[rr] + bias;
        t = 0.5f * t * (1.f + erff(t * 0.70710678118f));
        s_b2[(rowoff + 4 * lg + rr) * 68 + jt * 16 + lr] = f2bf(t);
      }
    }
  }
  __syncthreads();
  {
    Frag af = ldA(s_b2, rowoff + lr, lg);
    #pragma unroll
    for (int jtl = 0; jtl < 2; ++jtl) {
      int jt = jt0 + jtl;
      f32x4 acc = gemmW(af, W2, jt * 16 + lr, lg);
      float bias = b2[jt * 16 + lr];
      #pragma unroll
      for (int rr = 0; rr < 4; ++rr) {
        int m = rowoff + 4 * lg + rr;
        s_rs[m * 66 + jt * 16 + lr] = acc[rr] + bias + s_av[m * 66 + jt * 16 + lr];
      }
    }
  }
  __syncthreads();
  if (tid < 96) {
    int row = tid / 3, c = tid - row * 3;
    float acc = bout3[c];
    #pragma unroll 8
    for (int k = 0; k < 64; ++k)
      acc = fmaf(fmaxf(s_rs[row * 66 + k], 0.f), wout3[c * 64 + k], acc);
    Out[(size_t)(m0 + row) * 3 + c] = acc * mask[m0 + row];
  }
}

// ---------- host ----------
extern "C" void kernel_launch(void* const* d_in, const int* in_sizes, int n_in,
                              void* d_out, int out_size, void* d_ws, size_t ws_size,
                              hipStream_t stream)
{
  const float* pos    = (const float*)d_in[0];
  const float* t_int  = (const float*)d_in[1];
  const float* nmask  = (const float*)d_in[2];
  const float* w_in   = (const float*)d_in[3];
  const float* b_in   = (const float*)d_in[4];
  const float* w_mid  = (const float*)d_in[5];
  const float* b_mid  = (const float*)d_in[6];
  const float* w_out  = (const float*)d_in[7];
  const float* b_out  = (const float*)d_in[8];
  const float* e1w    = (const float*)d_in[9];
  const float* e1b    = (const float*)d_in[10];
  const float* e2w    = (const float*)d_in[11];
  const float* e2b    = (const float*)d_in[12];
  const float* const* SA1 = (const float* const*)(d_in + 13);
  const float* const* SA2 = (const float* const*)(d_in + 25);

  float* ws    = (float*)d_ws;
  float* temb1 = ws;
  float* temb2 = ws + 1024;
  float* X     = ws + 2048;
  float* X2    = X + (size_t)M_TOT * 64;
  ushort_t* ub = (ushort_t*)(X2 + (size_t)M_TOT * 64);
  ushort_t* Qb = ub;
  ushort_t* Kb = Qb + (size_t)BB * NH * NN * 16;
  ushort_t* VT = Kb + (size_t)BB * NH * NN * 16;
  ushort_t* Ab = VT + (size_t)BB * NH * NN * 16;
  ushort_t* Wb = Ab + (size_t)M_TOT * 64;
  ushort_t* Wqkv1 = Wb;
  ushort_t* Wo1   = Wb + 12288;
  ushort_t* W1_1  = Wb + 16384;
  ushort_t* W2_1  = Wb + 20480;
  ushort_t* Wqkv2 = Wb + 24576;
  ushort_t* Wo2   = Wb + 36864;
  ushort_t* W1_2  = Wb + 40960;
  ushort_t* W2_2  = Wb + 45056;
  ushort_t* Wmid  = Wb + 49152;

  prep_kernel<<<dim3(16, 10), 256, 0, stream>>>(
      SA1[2], SA1[4], SA1[8], SA1[10], SA2[2], SA2[4], SA2[8], SA2[10], w_mid, Wb,
      t_int, e1w, e1b, e2w, e2b, temb1, temb2);

  qkv1_kernel<<<M_TOT / 32, 256, 0, stream>>>(
      pos, w_in, b_in, temb1, X, SA1[0], SA1[1], Wqkv1, SA1[3], Qb, Kb, VT);
  attn_kernel<<<BB * NH * 16, 256, 0, stream>>>(Qb, Kb, VT, Ab);
  ffnq_kernel<<<M_TOT / 32, 256, 0, stream>>>(
      Ab, X, Wo1, SA1[5], SA1[6], SA1[7], W1_1, SA1[9], W2_1, SA1[11],
      Wmid, b_mid, temb2, SA2[0], SA2[1], Wqkv2, SA2[3], X2, Qb, Kb, VT);
  attn_kernel<<<BB * NH * 16, 256, 0, stream>>>(Qb, Kb, VT, Ab);
  ffn_final_kernel<<<M_TOT / 32, 256, 0, stream>>>(
      Ab, X2, Wo2, SA2[5], SA2[6], SA2[7], W1_2, SA2[9], W2_2, SA2[11],
      w_out, b_out, nmask, (float*)d_out);
}